// Round 1
// baseline (1223.255 us; speedup 1.0000x reference)
//
#include <hip/hip_runtime.h>

typedef __attribute__((ext_vector_type(8))) short short8;
typedef __attribute__((ext_vector_type(4))) float f32x4;
typedef __attribute__((ext_vector_type(4))) unsigned short us4;

__device__ __forceinline__ unsigned short f2bf(float f) {
  union { float f; unsigned u; } v; v.f = f;
  unsigned r = v.u + 0x7fffu + ((v.u >> 16) & 1u);
  return (unsigned short)(r >> 16);
}
__device__ __forceinline__ float bf2f(unsigned short b) {
  union { unsigned u; float f; } v; v.u = ((unsigned)b) << 16;
  return v.f;
}

__device__ __forceinline__ void gload_lds16(const void* g, void* l) {
  __builtin_amdgcn_global_load_lds((const __attribute__((address_space(1))) void*)g,
                                   (__attribute__((address_space(3))) void*)l,
                                   16, 0, 0);
}

// ---------------------------------------------------------------------------
// C[M,N] = A[M,K] @ B[N,K]^T   (bf16 in, fp32 accum), 128x128 tile, BK=32.
// EPI: 0 plain bf16 out; 1 transposed bf16 out (outb[col*ldo+row], pack4);
//      2 silu bf16 out; 3 out = v*aux (bf16, in-place ok);
//      4 outf[idx] += v (fp32 residual add); 5 t=v+aux; outf=t; outb=bf16(t)
// ---------------------------------------------------------------------------
template<int EPI>
__global__ __launch_bounds__(256) void gemm_bt(
    const unsigned short* __restrict__ A,
    const unsigned short* __restrict__ B,
    int M, int N, int K,
    unsigned short* __restrict__ outb,
    float* __restrict__ outf,
    const unsigned short* __restrict__ aux,
    int ldo)
{
  __shared__ __align__(16) unsigned short sA[128 * 32];
  __shared__ __align__(16) unsigned short sB[128 * 32];
  const int tid = threadIdx.x;
  const int lane = tid & 63;
  const int w = tid >> 6;
  const int wr = w >> 1, wc = w & 1;
  const int ln = lane & 15, qo = lane >> 4;
  const size_t m0 = (size_t)blockIdx.y * 128, n0 = (size_t)blockIdx.x * 128;

  // staging: wave w owns 1KB chunks {2w, 2w+1} of each tile
  const int sr0 = (2 * w) * 16 + (lane >> 2);
  const int sc  = (lane & 3) * 8;
  const unsigned short* Ap0 = A + (m0 + sr0) * K + sc;
  const unsigned short* Ap1 = A + (m0 + sr0 + 16) * K + sc;
  const unsigned short* Bp0 = B + (n0 + sr0) * K + sc;
  const unsigned short* Bp1 = B + (n0 + sr0 + 16) * K + sc;
  unsigned short* dA0 = &sA[(2 * w) * 512];
  unsigned short* dA1 = &sA[(2 * w + 1) * 512];
  unsigned short* dB0 = &sB[(2 * w) * 512];
  unsigned short* dB1 = &sB[(2 * w + 1) * 512];

  const f32x4 z4 = {0.f, 0.f, 0.f, 0.f};
  f32x4 acc[4][4];
#pragma unroll
  for (int i = 0; i < 4; i++)
#pragma unroll
    for (int j = 0; j < 4; j++) acc[i][j] = z4;

  for (int k0 = 0; k0 < K; k0 += 32) {
    gload_lds16(Ap0 + k0, dA0);
    gload_lds16(Ap1 + k0, dA1);
    gload_lds16(Bp0 + k0, dB0);
    gload_lds16(Bp1 + k0, dB1);
    __syncthreads();
    short8 af[4], bfv[4];
#pragma unroll
    for (int mi = 0; mi < 4; mi++)
      af[mi] = *(const short8*)&sA[(wr * 64 + mi * 16 + ln) * 32 + qo * 8];
#pragma unroll
    for (int ni = 0; ni < 4; ni++)
      bfv[ni] = *(const short8*)&sB[(wc * 64 + ni * 16 + ln) * 32 + qo * 8];
#pragma unroll
    for (int mi = 0; mi < 4; mi++)
#pragma unroll
      for (int ni = 0; ni < 4; ni++)
        acc[mi][ni] = __builtin_amdgcn_mfma_f32_16x16x32_bf16(af[mi], bfv[ni], acc[mi][ni], 0, 0, 0);
    __syncthreads();
  }

#pragma unroll
  for (int mi = 0; mi < 4; mi++) {
#pragma unroll
    for (int ni = 0; ni < 4; ni++) {
      const size_t row4 = m0 + wr * 64 + mi * 16 + qo * 4;
      const size_t col  = n0 + wc * 64 + ni * 16 + ln;
      if (EPI == 1) {
        us4 pk;
        pk[0] = f2bf(acc[mi][ni][0]); pk[1] = f2bf(acc[mi][ni][1]);
        pk[2] = f2bf(acc[mi][ni][2]); pk[3] = f2bf(acc[mi][ni][3]);
        *(us4*)&outb[col * (size_t)ldo + row4] = pk;
      } else {
#pragma unroll
        for (int r = 0; r < 4; r++) {
          const size_t idx = (row4 + r) * (size_t)ldo + col;
          float v = acc[mi][ni][r];
          if (EPI == 0) outb[idx] = f2bf(v);
          if (EPI == 2) outb[idx] = f2bf(v / (1.f + __expf(-v)));
          if (EPI == 3) outb[idx] = f2bf(v * bf2f(aux[idx]));
          if (EPI == 4) outf[idx] += v;
          if (EPI == 5) { float t = v + bf2f(aux[idx]); outf[idx] = t; outb[idx] = f2bf(t); }
        }
      }
    }
  }
}

// ---------------------------------------------------------------------------
// Flash attention, no mask. Grid: (8 q-blocks of 128, 32 heads). 4 waves,
// each wave owns 32 q rows. Swapped QK^T: S^T = mfma(K, Q) so softmax
// reduction over keys needs only shfl_xor(16/32). P staged in LDS row-major
// [q][key] so PV A-operand reads are contiguous. V is consumed from Vt
// (HD-major, [512][3072]) so PV B-operand reads are contiguous.
// ---------------------------------------------------------------------------
__global__ __launch_bounds__(256) void attn_k(
    const unsigned short* __restrict__ Q,   // 1024 x 2048
    const unsigned short* __restrict__ Kb,  // 3072 x 512
    const unsigned short* __restrict__ Vt,  // 512 x 3072
    unsigned short* __restrict__ O)         // 1024 x 2048
{
  __shared__ __align__(16) unsigned short sK[128 * 72];
  __shared__ __align__(16) unsigned short sV[64 * 136];
  __shared__ __align__(16) unsigned short sP[128 * 136];
  const int tid = threadIdx.x;
  const int lane = tid & 63, w = tid >> 6;
  const int ln = lane & 15, qo = lane >> 4;
  const int head = blockIdx.y;
  const int kvh = head >> 2;
  const int q0w = blockIdx.x * 128 + w * 32;

  // Q fragments (B-operand of swapped QK), pre-scaled by HD^-0.5 = 1/8 (exact)
  short8 qf[2][2];
#pragma unroll
  for (int nq = 0; nq < 2; nq++)
#pragma unroll
    for (int kc = 0; kc < 2; kc++) {
      short8 t = *(const short8*)&Q[(size_t)(q0w + nq * 16 + ln) * 2048 + head * 64 + kc * 32 + qo * 8];
#pragma unroll
      for (int i = 0; i < 8; i++)
        t[i] = (short)f2bf(bf2f((unsigned short)t[i]) * 0.125f);
      qf[nq][kc] = t;
    }

  const f32x4 z4 = {0.f, 0.f, 0.f, 0.f};
  f32x4 oacc[2][4];
#pragma unroll
  for (int a = 0; a < 2; a++)
#pragma unroll
    for (int b = 0; b < 4; b++) oacc[a][b] = z4;
  float mrun[2] = {-1e30f, -1e30f}, lrun[2] = {0.f, 0.f};

  for (int t0 = 0; t0 < 3072; t0 += 128) {
    // stage K tile [128 keys][64 hd] and Vt tile [64 hd][128 keys], padded rows
#pragma unroll
    for (int j = 0; j < 4; j++) {
      int idx = j * 256 + tid;
      int kr = idx >> 3, kc8 = idx & 7;
      *(short8*)&sK[kr * 72 + kc8 * 8] =
          *(const short8*)&Kb[(size_t)(t0 + kr) * 512 + kvh * 64 + kc8 * 8];
      int vr = idx >> 4, vc = idx & 15;
      *(short8*)&sV[vr * 136 + vc * 8] =
          *(const short8*)&Vt[(size_t)(kvh * 64 + vr) * 3072 + t0 + vc * 8];
    }
    __syncthreads();

    // S^T[key][q] = K * Q^T
    f32x4 sacc[8][2];
#pragma unroll
    for (int mi = 0; mi < 8; mi++) { sacc[mi][0] = z4; sacc[mi][1] = z4; }
#pragma unroll
    for (int kc = 0; kc < 2; kc++)
#pragma unroll
      for (int mi = 0; mi < 8; mi++) {
        short8 kf = *(const short8*)&sK[(mi * 16 + ln) * 72 + kc * 32 + qo * 8];
        sacc[mi][0] = __builtin_amdgcn_mfma_f32_16x16x32_bf16(kf, qf[0][kc], sacc[mi][0], 0, 0, 0);
        sacc[mi][1] = __builtin_amdgcn_mfma_f32_16x16x32_bf16(kf, qf[1][kc], sacc[mi][1], 0, 0, 0);
      }

    // online softmax (per lane: q = nq*16 + ln; keys spread over mi, r, quarters)
    float alpha[2];
#pragma unroll
    for (int nq = 0; nq < 2; nq++) {
      float tm = -1e30f;
#pragma unroll
      for (int mi = 0; mi < 8; mi++)
#pragma unroll
        for (int r = 0; r < 4; r++) tm = fmaxf(tm, sacc[mi][nq][r]);
      tm = fmaxf(tm, __shfl_xor(tm, 16));
      tm = fmaxf(tm, __shfl_xor(tm, 32));
      float mn = fmaxf(mrun[nq], tm);
      float al = __expf(mrun[nq] - mn);
      float ts = 0.f;
#pragma unroll
      for (int mi = 0; mi < 8; mi++) {
        us4 pk;
#pragma unroll
        for (int r = 0; r < 4; r++) {
          float pv = __expf(sacc[mi][nq][r] - mn);
          ts += pv;
          pk[r] = f2bf(pv);
        }
        // P[q][key]: 4 consecutive keys packed per write
        *(us4*)&sP[(size_t)(w * 32 + nq * 16 + ln) * 136 + mi * 16 + qo * 4] = pk;
      }
      ts += __shfl_xor(ts, 16);
      ts += __shfl_xor(ts, 32);
      lrun[nq] = lrun[nq] * al + ts;
      mrun[nq] = mn;
      alpha[nq] = al;
    }

    // rescale O accumulator (O rows are q = miq*16 + qo*4 + r)
#pragma unroll
    for (int miq = 0; miq < 2; miq++)
#pragma unroll
      for (int r = 0; r < 4; r++) {
        float ar = __shfl(alpha[miq], qo * 4 + r);
#pragma unroll
        for (int ni = 0; ni < 4; ni++) oacc[miq][ni][r] *= ar;
      }

    // PV: O[q][hd] += P[q][keys] * V[keys][hd]
#pragma unroll
    for (int ks = 0; ks < 4; ks++) {
      short8 pf0 = *(const short8*)&sP[(size_t)(w * 32 + 0 * 16 + ln) * 136 + ks * 32 + qo * 8];
      short8 pf1 = *(const short8*)&sP[(size_t)(w * 32 + 1 * 16 + ln) * 136 + ks * 32 + qo * 8];
      short8 vf[4];
#pragma unroll
      for (int ni = 0; ni < 4; ni++)
        vf[ni] = *(const short8*)&sV[(ni * 16 + ln) * 136 + ks * 32 + qo * 8];
#pragma unroll
      for (int ni = 0; ni < 4; ni++) {
        oacc[0][ni] = __builtin_amdgcn_mfma_f32_16x16x32_bf16(pf0, vf[ni], oacc[0][ni], 0, 0, 0);
        oacc[1][ni] = __builtin_amdgcn_mfma_f32_16x16x32_bf16(pf1, vf[ni], oacc[1][ni], 0, 0, 0);
      }
    }
    __syncthreads();
  }

  float linv[2] = {1.f / lrun[0], 1.f / lrun[1]};
#pragma unroll
  for (int miq = 0; miq < 2; miq++)
#pragma unroll
    for (int r = 0; r < 4; r++) {
      float lr = __shfl(linv[miq], qo * 4 + r);
#pragma unroll
      for (int ni = 0; ni < 4; ni++) {
        float v = oacc[miq][ni][r] * lr;
        O[(size_t)(q0w + miq * 16 + qo * 4 + r) * 2048 + head * 64 + ni * 16 + ln] = f2bf(v);
      }
    }
}

// ---------------------------------------------------------------------------
__global__ __launch_bounds__(256) void rmsnorm_k(const float* __restrict__ in,
                                                 const float* __restrict__ w,
                                                 unsigned short* __restrict__ out) {
  const int row = blockIdx.x;
  const int tid = threadIdx.x;
  const float* x = in + (size_t)row * 2048;
  float4 a = ((const float4*)x)[tid * 2];
  float4 b = ((const float4*)x)[tid * 2 + 1];
  float ss = a.x * a.x + a.y * a.y + a.z * a.z + a.w * a.w +
             b.x * b.x + b.y * b.y + b.z * b.z + b.w * b.w;
#pragma unroll
  for (int d = 1; d < 64; d <<= 1) ss += __shfl_xor(ss, d);
  __shared__ float red[4];
  if ((tid & 63) == 0) red[tid >> 6] = ss;
  __syncthreads();
  float sc = rsqrtf((red[0] + red[1] + red[2] + red[3]) * (1.f / 2048.f) + 1e-6f);
  float4 wa = ((const float4*)w)[tid * 2];
  float4 wb = ((const float4*)w)[tid * 2 + 1];
  us4 o1, o2;
  o1[0] = f2bf(a.x * sc * wa.x); o1[1] = f2bf(a.y * sc * wa.y);
  o1[2] = f2bf(a.z * sc * wa.z); o1[3] = f2bf(a.w * sc * wa.w);
  o2[0] = f2bf(b.x * sc * wb.x); o2[1] = f2bf(b.y * sc * wb.y);
  o2[2] = f2bf(b.z * sc * wb.z); o2[3] = f2bf(b.w * sc * wb.w);
  us4* op = (us4*)&out[(size_t)row * 2048 + tid * 8];
  op[0] = o1; op[1] = o2;
}

__global__ __launch_bounds__(256) void cvt_k(const float* __restrict__ in,
                                             unsigned short* __restrict__ out, int n4) {
  int i = blockIdx.x * 256 + threadIdx.x;
  const int stride = gridDim.x * 256;
  for (; i < n4; i += stride) {
    float4 v = ((const float4*)in)[i];
    us4 o;
    o[0] = f2bf(v.x); o[1] = f2bf(v.y); o[2] = f2bf(v.z); o[3] = f2bf(v.w);
    ((us4*)out)[i] = o;
  }
}

__global__ __launch_bounds__(256) void initct_k(const float* __restrict__ hidden,
                                                float* __restrict__ ctf,
                                                unsigned short* __restrict__ ctb) {
  int i = blockIdx.x * 256 + threadIdx.x;
  const int stride = gridDim.x * 256;
  for (; i < 524288; i += stride) {  // 1024*2048/4, rows T-S..T of hidden
    float4 v = ((const float4*)hidden)[524288 + i];
    ((float4*)ctf)[i] = v;
    us4 o;
    o[0] = f2bf(v.x); o[1] = f2bf(v.y); o[2] = f2bf(v.z); o[3] = f2bf(v.w);
    ((us4*)ctb)[i] = o;
  }
}

// ---------------------------------------------------------------------------
extern "C" void kernel_launch(void* const* d_in, const int* in_sizes, int n_in,
                              void* d_out, int out_size, void* d_ws, size_t ws_size,
                              hipStream_t stream) {
  (void)in_sizes; (void)n_in; (void)out_size; (void)ws_size;
  const float* hidden = (const float*)d_in[0];
  const float* q_w  = (const float*)d_in[1];
  const float* k_w  = (const float*)d_in[2];
  const float* v_w  = (const float*)d_in[3];
  const float* o_w  = (const float*)d_in[4];
  const float* a_nw = (const float*)d_in[5];
  const float* m_nw = (const float*)d_in[6];
  const float* g_w  = (const float*)d_in[7];
  const float* u_w  = (const float*)d_in[8];
  const float* dn_w = (const float*)d_in[9];
  float* out = (float*)d_out;

  char* p = (char*)d_ws;
  size_t off = 0;
  auto take = [&](size_t bytes) -> char* {
    char* r = p + off;
    off += (bytes + 255) & ~(size_t)255;
    return r;
  };
  float* ctf          = (float*)take((size_t)1024 * 2048 * 4);
  unsigned short* ctb = (unsigned short*)take((size_t)1024 * 2048 * 2);
  unsigned short* xb  = (unsigned short*)take((size_t)1024 * 2048 * 2);
  unsigned short* hb  = (unsigned short*)take((size_t)2048 * 2048 * 2);
  unsigned short* qwB = (unsigned short*)take((size_t)2048 * 2048 * 2);
  unsigned short* kwB = (unsigned short*)take((size_t)512 * 2048 * 2);
  unsigned short* vwB = (unsigned short*)take((size_t)512 * 2048 * 2);
  unsigned short* owB = (unsigned short*)take((size_t)2048 * 2048 * 2);
  unsigned short* gwB = (unsigned short*)take((size_t)5632 * 2048 * 2);
  unsigned short* uwB = (unsigned short*)take((size_t)5632 * 2048 * 2);
  unsigned short* dwB = (unsigned short*)take((size_t)2048 * 5632 * 2);
  unsigned short* qB  = (unsigned short*)take((size_t)1024 * 2048 * 2);
  unsigned short* kB  = (unsigned short*)take((size_t)3072 * 512 * 2);
  unsigned short* vtB = (unsigned short*)take((size_t)512 * 3072 * 2);
  unsigned short* oB  = (unsigned short*)take((size_t)1024 * 2048 * 2);
  unsigned short* gtB = (unsigned short*)take((size_t)1024 * 5632 * 2);

  dim3 blk(256);
  auto cvt = [&](const float* src, unsigned short* dst, size_t n) {
    int n4 = (int)(n / 4);
    int g = (n4 + 255) / 256; if (g > 1024) g = 1024;
    cvt_k<<<dim3(g), blk, 0, stream>>>(src, dst, n4);
  };
  cvt(q_w, qwB, (size_t)2048 * 2048);
  cvt(k_w, kwB, (size_t)512 * 2048);
  cvt(v_w, vwB, (size_t)512 * 2048);
  cvt(o_w, owB, (size_t)2048 * 2048);
  cvt(g_w, gwB, (size_t)5632 * 2048);
  cvt(u_w, uwB, (size_t)5632 * 2048);
  cvt(dn_w, dwB, (size_t)2048 * 5632);
  cvt(hidden, hb, (size_t)2048 * 2048);
  initct_k<<<dim3(1024), blk, 0, stream>>>(hidden, ctf, ctb);

  // K/V of the fixed hidden prefix (rows/cols 0..2047): identical both layers
  gemm_bt<0><<<dim3(4, 16), blk, 0, stream>>>(hb, kwB, 2048, 512, 2048, kB, nullptr, nullptr, 512);
  gemm_bt<1><<<dim3(4, 16), blk, 0, stream>>>(hb, vwB, 2048, 512, 2048, vtB, nullptr, nullptr, 3072);

  for (int it = 0; it < 2; it++) {
    rmsnorm_k<<<dim3(1024), blk, 0, stream>>>(ctf, a_nw, xb);
    gemm_bt<0><<<dim3(16, 8), blk, 0, stream>>>(xb, qwB, 1024, 2048, 2048, qB, nullptr, nullptr, 2048);
    gemm_bt<0><<<dim3(4, 8), blk, 0, stream>>>(ctb, kwB, 1024, 512, 2048, kB + (size_t)2048 * 512, nullptr, nullptr, 512);
    gemm_bt<1><<<dim3(4, 8), blk, 0, stream>>>(ctb, vwB, 1024, 512, 2048, vtB + 2048, nullptr, nullptr, 3072);
    attn_k<<<dim3(8, 32), blk, 0, stream>>>(qB, kB, vtB, oB);
    gemm_bt<4><<<dim3(16, 8), blk, 0, stream>>>(oB, owB, 1024, 2048, 2048, nullptr, ctf, nullptr, 2048);
    rmsnorm_k<<<dim3(1024), blk, 0, stream>>>(ctf, m_nw, xb);
    gemm_bt<2><<<dim3(44, 8), blk, 0, stream>>>(xb, gwB, 1024, 5632, 2048, gtB, nullptr, nullptr, 5632);
    gemm_bt<3><<<dim3(44, 8), blk, 0, stream>>>(xb, uwB, 1024, 5632, 2048, gtB, nullptr, gtB, 5632);
    gemm_bt<5><<<dim3(16, 8), blk, 0, stream>>>(gtB, dwB, 1024, 2048, 5632, ctb,
                                                (it == 1 ? out : ctf), xb, 2048);
  }
}

// Round 2
// 964.146 us; speedup vs baseline: 1.2687x; 1.2687x over previous
//
#include <hip/hip_runtime.h>

typedef __attribute__((ext_vector_type(8))) short short8;
typedef __attribute__((ext_vector_type(4))) float f32x4;
typedef __attribute__((ext_vector_type(4))) unsigned short us4;

__device__ __forceinline__ unsigned short f2bf(float f) {
  union { float f; unsigned u; } v; v.f = f;
  unsigned r = v.u + 0x7fffu + ((v.u >> 16) & 1u);
  return (unsigned short)(r >> 16);
}
__device__ __forceinline__ float bf2f(unsigned short b) {
  union { unsigned u; float f; } v; v.u = ((unsigned)b) << 16;
  return v.f;
}

__device__ __forceinline__ void gload_lds16(const void* g, void* l) {
  __builtin_amdgcn_global_load_lds((const __attribute__((address_space(1))) void*)g,
                                   (__attribute__((address_space(3))) void*)l,
                                   16, 0, 0);
}

#define VMW6() asm volatile("s_waitcnt vmcnt(6)" ::: "memory")
#define VMW0() asm volatile("s_waitcnt vmcnt(0)" ::: "memory")

// Stage an R x 64 bf16 tile (row-major, 128B rows) into LDS, linear dest,
// inverse-XOR-swizzled global source (rule #21): LDS(row, cb) holds
// global(row, cb ^ ((row&7)<<4)).
template<int R>
__device__ __forceinline__ void stage64(const unsigned short* g, int K, int k0,
                                        unsigned short* lds, int tid) {
  const int lane = tid & 63, w = tid >> 6;
  constexpr int RW = R / 4;   // rows per wave
  constexpr int NL = RW / 8;  // loads per thread (8 rows / load)
#pragma unroll
  for (int i = 0; i < NL; i++) {
    const int r0 = w * RW + i * 8;
    const int row = r0 + (lane >> 3);
    const int colb = (((lane & 7) ^ (lane >> 3)) << 4);
    gload_lds16((const char*)(g + (size_t)row * K + k0) + colb, lds + r0 * 64);
  }
}

// Swizzled fragment read: returns global(row, cb..cb+15 bytes) of the tile.
__device__ __forceinline__ short8 lds_frag(const unsigned short* t, int row, int cb) {
  return *(const short8*)((const char*)t + row * 128 + (cb ^ ((row & 7) << 4)));
}

// ---------------------------------------------------------------------------
// C[M,N] = A[M,K] @ B[N,K]^T  (bf16 in, fp32 accum). BM=64, BN=128, BK=64,
// 3-buffer depth-2 pipeline with counted vmcnt. 4 waves, wave tile 32x64.
// EPI: 0 plain bf16; 1 transposed bf16 (outb[col*ldo+row], pack4);
//      2 silu bf16; 3 out = v*aux (bf16, in-place ok);
//      4 outf[idx] += v; 5 t=v+aux; outf=t; outb=bf16(t)
// ---------------------------------------------------------------------------
template<int EPI>
__global__ __launch_bounds__(256) void gemm_bt(
    const unsigned short* __restrict__ A,
    const unsigned short* __restrict__ B,
    int K,
    unsigned short* __restrict__ outb,
    float* __restrict__ outf,
    const unsigned short* __restrict__ aux,
    int ldo)
{
  constexpr int BM = 64, BN = 128, BK = 64;
  __shared__ __align__(16) unsigned short sA[3][BM * BK];
  __shared__ __align__(16) unsigned short sB[3][BN * BK];
  const int tid = threadIdx.x;
  const int lane = tid & 63, w = tid >> 6;
  const int wr = w >> 1, wc = w & 1;
  const int ln = lane & 15, qo = lane >> 4;
  const size_t m0 = (size_t)blockIdx.y * BM, n0 = (size_t)blockIdx.x * BN;
  const unsigned short* Ab = A + m0 * K;
  const unsigned short* Bb = B + n0 * K;

  const f32x4 z4 = {0.f, 0.f, 0.f, 0.f};
  f32x4 acc[2][4];
#pragma unroll
  for (int i = 0; i < 2; i++)
#pragma unroll
    for (int j = 0; j < 4; j++) acc[i][j] = z4;

  const int nt = K / BK;
  stage64<BM>(Ab, K, 0, sA[0], tid);
  stage64<BN>(Bb, K, 0, sB[0], tid);
  stage64<BM>(Ab, K, BK, sA[1], tid);
  stage64<BN>(Bb, K, BK, sB[1], tid);

  int cur = 0;
  for (int t = 0; t < nt; ++t) {
    if (t == nt - 1) VMW0(); else VMW6();
    __builtin_amdgcn_s_barrier();
    asm volatile("" ::: "memory");
    if (t + 2 < nt) {
      const int nx = (cur == 0) ? 2 : cur - 1;  // (cur+2)%3
      stage64<BM>(Ab, K, (t + 2) * BK, sA[nx], tid);
      stage64<BN>(Bb, K, (t + 2) * BK, sB[nx], tid);
    }
    const unsigned short* cA = sA[cur];
    const unsigned short* cB = sB[cur];
#pragma unroll
    for (int ks = 0; ks < 2; ks++) {
      short8 af[2], bfv[4];
#pragma unroll
      for (int mi = 0; mi < 2; mi++)
        af[mi] = lds_frag(cA, wr * 32 + mi * 16 + ln, ks * 64 + qo * 16);
#pragma unroll
      for (int ni = 0; ni < 4; ni++)
        bfv[ni] = lds_frag(cB, wc * 64 + ni * 16 + ln, ks * 64 + qo * 16);
#pragma unroll
      for (int mi = 0; mi < 2; mi++)
#pragma unroll
        for (int ni = 0; ni < 4; ni++)
          acc[mi][ni] = __builtin_amdgcn_mfma_f32_16x16x32_bf16(af[mi], bfv[ni], acc[mi][ni], 0, 0, 0);
    }
    cur = (cur == 2) ? 0 : cur + 1;
  }

#pragma unroll
  for (int mi = 0; mi < 2; mi++) {
#pragma unroll
    for (int ni = 0; ni < 4; ni++) {
      const size_t row4 = m0 + wr * 32 + mi * 16 + qo * 4;
      const size_t col  = n0 + wc * 64 + ni * 16 + ln;
      if (EPI == 1) {
        us4 pk;
        pk[0] = f2bf(acc[mi][ni][0]); pk[1] = f2bf(acc[mi][ni][1]);
        pk[2] = f2bf(acc[mi][ni][2]); pk[3] = f2bf(acc[mi][ni][3]);
        *(us4*)&outb[col * (size_t)ldo + row4] = pk;
      } else {
#pragma unroll
        for (int r = 0; r < 4; r++) {
          const size_t idx = (row4 + r) * (size_t)ldo + col;
          float v = acc[mi][ni][r];
          if (EPI == 0) outb[idx] = f2bf(v);
          if (EPI == 2) outb[idx] = f2bf(v / (1.f + __expf(-v)));
          if (EPI == 3) outb[idx] = f2bf(v * bf2f(aux[idx]));
          if (EPI == 4) outf[idx] += v;
          if (EPI == 5) { float t = v + bf2f(aux[idx]); outf[idx] = t; outb[idx] = f2bf(t); }
        }
      }
    }
  }
}

// ---------------------------------------------------------------------------
// Flash attention, no mask. Grid: (8 q-blocks of 128, 32 heads). 4 waves,
// each wave owns 32 q rows. Swapped QK^T (S^T = mfma(K,Q)).
// ---------------------------------------------------------------------------
__global__ __launch_bounds__(256) void attn_k(
    const unsigned short* __restrict__ Q,   // 1024 x 2048
    const unsigned short* __restrict__ Kb,  // 3072 x 512
    const unsigned short* __restrict__ Vt,  // 512 x 3072
    unsigned short* __restrict__ O)         // 1024 x 2048
{
  __shared__ __align__(16) unsigned short sK[128 * 72];
  __shared__ __align__(16) unsigned short sV[64 * 136];
  __shared__ __align__(16) unsigned short sP[128 * 136];
  const int tid = threadIdx.x;
  const int lane = tid & 63, w = tid >> 6;
  const int ln = lane & 15, qo = lane >> 4;
  const int head = blockIdx.y;
  const int kvh = head >> 2;
  const int q0w = blockIdx.x * 128 + w * 32;

  short8 qf[2][2];
#pragma unroll
  for (int nq = 0; nq < 2; nq++)
#pragma unroll
    for (int kc = 0; kc < 2; kc++) {
      short8 t = *(const short8*)&Q[(size_t)(q0w + nq * 16 + ln) * 2048 + head * 64 + kc * 32 + qo * 8];
#pragma unroll
      for (int i = 0; i < 8; i++)
        t[i] = (short)f2bf(bf2f((unsigned short)t[i]) * 0.125f);
      qf[nq][kc] = t;
    }

  const f32x4 z4 = {0.f, 0.f, 0.f, 0.f};
  f32x4 oacc[2][4];
#pragma unroll
  for (int a = 0; a < 2; a++)
#pragma unroll
    for (int b = 0; b < 4; b++) oacc[a][b] = z4;
  float mrun[2] = {-1e30f, -1e30f}, lrun[2] = {0.f, 0.f};

  for (int t0 = 0; t0 < 3072; t0 += 128) {
#pragma unroll
    for (int j = 0; j < 4; j++) {
      int idx = j * 256 + tid;
      int kr = idx >> 3, kc8 = idx & 7;
      *(short8*)&sK[kr * 72 + kc8 * 8] =
          *(const short8*)&Kb[(size_t)(t0 + kr) * 512 + kvh * 64 + kc8 * 8];
      int vr = idx >> 4, vc = idx & 15;
      *(short8*)&sV[vr * 136 + vc * 8] =
          *(const short8*)&Vt[(size_t)(kvh * 64 + vr) * 3072 + t0 + vc * 8];
    }
    __syncthreads();

    f32x4 sacc[8][2];
#pragma unroll
    for (int mi = 0; mi < 8; mi++) { sacc[mi][0] = z4; sacc[mi][1] = z4; }
#pragma unroll
    for (int kc = 0; kc < 2; kc++)
#pragma unroll
      for (int mi = 0; mi < 8; mi++) {
        short8 kf = *(const short8*)&sK[(mi * 16 + ln) * 72 + kc * 32 + qo * 8];
        sacc[mi][0] = __builtin_amdgcn_mfma_f32_16x16x32_bf16(kf, qf[0][kc], sacc[mi][0], 0, 0, 0);
        sacc[mi][1] = __builtin_amdgcn_mfma_f32_16x16x32_bf16(kf, qf[1][kc], sacc[mi][1], 0, 0, 0);
      }

    float alpha[2];
#pragma unroll
    for (int nq = 0; nq < 2; nq++) {
      float tm = -1e30f;
#pragma unroll
      for (int mi = 0; mi < 8; mi++)
#pragma unroll
        for (int r = 0; r < 4; r++) tm = fmaxf(tm, sacc[mi][nq][r]);
      tm = fmaxf(tm, __shfl_xor(tm, 16));
      tm = fmaxf(tm, __shfl_xor(tm, 32));
      float mn = fmaxf(mrun[nq], tm);
      float al = __expf(mrun[nq] - mn);
      float ts = 0.f;
#pragma unroll
      for (int mi = 0; mi < 8; mi++) {
        us4 pk;
#pragma unroll
        for (int r = 0; r < 4; r++) {
          float pv = __expf(sacc[mi][nq][r] - mn);
          ts += pv;
          pk[r] = f2bf(pv);
        }
        *(us4*)&sP[(size_t)(w * 32 + nq * 16 + ln) * 136 + mi * 16 + qo * 4] = pk;
      }
      ts += __shfl_xor(ts, 16);
      ts += __shfl_xor(ts, 32);
      lrun[nq] = lrun[nq] * al + ts;
      mrun[nq] = mn;
      alpha[nq] = al;
    }

#pragma unroll
    for (int miq = 0; miq < 2; miq++)
#pragma unroll
      for (int r = 0; r < 4; r++) {
        float ar = __shfl(alpha[miq], qo * 4 + r);
#pragma unroll
        for (int ni = 0; ni < 4; ni++) oacc[miq][ni][r] *= ar;
      }

#pragma unroll
    for (int ks = 0; ks < 4; ks++) {
      short8 pf0 = *(const short8*)&sP[(size_t)(w * 32 + 0 * 16 + ln) * 136 + ks * 32 + qo * 8];
      short8 pf1 = *(const short8*)&sP[(size_t)(w * 32 + 1 * 16 + ln) * 136 + ks * 32 + qo * 8];
      short8 vf[4];
#pragma unroll
      for (int ni = 0; ni < 4; ni++)
        vf[ni] = *(const short8*)&sV[(ni * 16 + ln) * 136 + ks * 32 + qo * 8];
#pragma unroll
      for (int ni = 0; ni < 4; ni++) {
        oacc[0][ni] = __builtin_amdgcn_mfma_f32_16x16x32_bf16(pf0, vf[ni], oacc[0][ni], 0, 0, 0);
        oacc[1][ni] = __builtin_amdgcn_mfma_f32_16x16x32_bf16(pf1, vf[ni], oacc[1][ni], 0, 0, 0);
      }
    }
    __syncthreads();
  }

  float linv[2] = {1.f / lrun[0], 1.f / lrun[1]};
#pragma unroll
  for (int miq = 0; miq < 2; miq++)
#pragma unroll
    for (int r = 0; r < 4; r++) {
      float lr = __shfl(linv[miq], qo * 4 + r);
#pragma unroll
      for (int ni = 0; ni < 4; ni++) {
        float v = oacc[miq][ni][r] * lr;
        O[(size_t)(q0w + miq * 16 + qo * 4 + r) * 2048 + head * 64 + ni * 16 + ln] = f2bf(v);
      }
    }
}

// ---------------------------------------------------------------------------
__global__ __launch_bounds__(256) void rmsnorm_k(const float* __restrict__ in,
                                                 const float* __restrict__ w,
                                                 unsigned short* __restrict__ out) {
  const int row = blockIdx.x;
  const int tid = threadIdx.x;
  const float* x = in + (size_t)row * 2048;
  float4 a = ((const float4*)x)[tid * 2];
  float4 b = ((const float4*)x)[tid * 2 + 1];
  float ss = a.x * a.x + a.y * a.y + a.z * a.z + a.w * a.w +
             b.x * b.x + b.y * b.y + b.z * b.z + b.w * b.w;
#pragma unroll
  for (int d = 1; d < 64; d <<= 1) ss += __shfl_xor(ss, d);
  __shared__ float red[4];
  if ((tid & 63) == 0) red[tid >> 6] = ss;
  __syncthreads();
  float sc = rsqrtf((red[0] + red[1] + red[2] + red[3]) * (1.f / 2048.f) + 1e-6f);
  float4 wa = ((const float4*)w)[tid * 2];
  float4 wb = ((const float4*)w)[tid * 2 + 1];
  us4 o1, o2;
  o1[0] = f2bf(a.x * sc * wa.x); o1[1] = f2bf(a.y * sc * wa.y);
  o1[2] = f2bf(a.z * sc * wa.z); o1[3] = f2bf(a.w * sc * wa.w);
  o2[0] = f2bf(b.x * sc * wb.x); o2[1] = f2bf(b.y * sc * wb.y);
  o2[2] = f2bf(b.z * sc * wb.z); o2[3] = f2bf(b.w * sc * wb.w);
  us4* op = (us4*)&out[(size_t)row * 2048 + tid * 8];
  op[0] = o1; op[1] = o2;
}

__global__ __launch_bounds__(256) void cvt_k(const float* __restrict__ in,
                                             unsigned short* __restrict__ out, int n4) {
  int i = blockIdx.x * 256 + threadIdx.x;
  const int stride = gridDim.x * 256;
  for (; i < n4; i += stride) {
    float4 v = ((const float4*)in)[i];
    us4 o;
    o[0] = f2bf(v.x); o[1] = f2bf(v.y); o[2] = f2bf(v.z); o[3] = f2bf(v.w);
    ((us4*)out)[i] = o;
  }
}

__global__ __launch_bounds__(256) void initct_k(const float* __restrict__ hidden,
                                                float* __restrict__ ctf,
                                                unsigned short* __restrict__ ctb) {
  int i = blockIdx.x * 256 + threadIdx.x;
  const int stride = gridDim.x * 256;
  for (; i < 524288; i += stride) {
    float4 v = ((const float4*)hidden)[524288 + i];
    ((float4*)ctf)[i] = v;
    us4 o;
    o[0] = f2bf(v.x); o[1] = f2bf(v.y); o[2] = f2bf(v.z); o[3] = f2bf(v.w);
    ((us4*)ctb)[i] = o;
  }
}

// ---------------------------------------------------------------------------
extern "C" void kernel_launch(void* const* d_in, const int* in_sizes, int n_in,
                              void* d_out, int out_size, void* d_ws, size_t ws_size,
                              hipStream_t stream) {
  (void)in_sizes; (void)n_in; (void)out_size; (void)ws_size;
  const float* hidden = (const float*)d_in[0];
  const float* q_w  = (const float*)d_in[1];
  const float* k_w  = (const float*)d_in[2];
  const float* v_w  = (const float*)d_in[3];
  const float* o_w  = (const float*)d_in[4];
  const float* a_nw = (const float*)d_in[5];
  const float* m_nw = (const float*)d_in[6];
  const float* g_w  = (const float*)d_in[7];
  const float* u_w  = (const float*)d_in[8];
  const float* dn_w = (const float*)d_in[9];
  float* out = (float*)d_out;

  char* p = (char*)d_ws;
  size_t off = 0;
  auto take = [&](size_t bytes) -> char* {
    char* r = p + off;
    off += (bytes + 255) & ~(size_t)255;
    return r;
  };
  float* ctf          = (float*)take((size_t)1024 * 2048 * 4);
  unsigned short* ctb = (unsigned short*)take((size_t)1024 * 2048 * 2);
  unsigned short* xb  = (unsigned short*)take((size_t)1024 * 2048 * 2);
  unsigned short* hb  = (unsigned short*)take((size_t)2048 * 2048 * 2);
  unsigned short* qwB = (unsigned short*)take((size_t)2048 * 2048 * 2);
  unsigned short* kwB = (unsigned short*)take((size_t)512 * 2048 * 2);
  unsigned short* vwB = (unsigned short*)take((size_t)512 * 2048 * 2);
  unsigned short* owB = (unsigned short*)take((size_t)2048 * 2048 * 2);
  unsigned short* gwB = (unsigned short*)take((size_t)5632 * 2048 * 2);
  unsigned short* uwB = (unsigned short*)take((size_t)5632 * 2048 * 2);
  unsigned short* dwB = (unsigned short*)take((size_t)2048 * 5632 * 2);
  unsigned short* qB  = (unsigned short*)take((size_t)1024 * 2048 * 2);
  unsigned short* kB  = (unsigned short*)take((size_t)3072 * 512 * 2);
  unsigned short* vtB = (unsigned short*)take((size_t)512 * 3072 * 2);
  unsigned short* oB  = (unsigned short*)take((size_t)1024 * 2048 * 2);
  unsigned short* gtB = (unsigned short*)take((size_t)1024 * 5632 * 2);

  dim3 blk(256);
  auto cvt = [&](const float* src, unsigned short* dst, size_t n) {
    int n4 = (int)(n / 4);
    int g = (n4 + 255) / 256; if (g > 1024) g = 1024;
    cvt_k<<<dim3(g), blk, 0, stream>>>(src, dst, n4);
  };
  cvt(q_w, qwB, (size_t)2048 * 2048);
  cvt(k_w, kwB, (size_t)512 * 2048);
  cvt(v_w, vwB, (size_t)512 * 2048);
  cvt(o_w, owB, (size_t)2048 * 2048);
  cvt(g_w, gwB, (size_t)5632 * 2048);
  cvt(u_w, uwB, (size_t)5632 * 2048);
  cvt(dn_w, dwB, (size_t)2048 * 5632);
  cvt(hidden, hb, (size_t)2048 * 2048);
  initct_k<<<dim3(1024), blk, 0, stream>>>(hidden, ctf, ctb);

  // K/V of the fixed hidden prefix (rows 0..2047): identical both layers
  gemm_bt<0><<<dim3(4, 32), blk, 0, stream>>>(hb, kwB, 2048, kB, nullptr, nullptr, 512);
  gemm_bt<1><<<dim3(4, 32), blk, 0, stream>>>(hb, vwB, 2048, vtB, nullptr, nullptr, 3072);

  for (int it = 0; it < 2; it++) {
    rmsnorm_k<<<dim3(1024), blk, 0, stream>>>(ctf, a_nw, xb);
    gemm_bt<0><<<dim3(16, 16), blk, 0, stream>>>(xb, qwB, 2048, qB, nullptr, nullptr, 2048);
    gemm_bt<0><<<dim3(4, 16), blk, 0, stream>>>(ctb, kwB, 2048, kB + (size_t)2048 * 512, nullptr, nullptr, 512);
    gemm_bt<1><<<dim3(4, 16), blk, 0, stream>>>(ctb, vwB, 2048, vtB + 2048, nullptr, nullptr, 3072);
    attn_k<<<dim3(8, 32), blk, 0, stream>>>(qB, kB, vtB, oB);
    gemm_bt<4><<<dim3(16, 16), blk, 0, stream>>>(oB, owB, 2048, nullptr, ctf, nullptr, 2048);
    rmsnorm_k<<<dim3(1024), blk, 0, stream>>>(ctf, m_nw, xb);
    gemm_bt<2><<<dim3(44, 16), blk, 0, stream>>>(xb, gwB, 2048, gtB, nullptr, nullptr, 5632);
    gemm_bt<3><<<dim3(44, 16), blk, 0, stream>>>(xb, uwB, 2048, gtB, nullptr, gtB, 5632);
    gemm_bt<5><<<dim3(16, 16), blk, 0, stream>>>(gtB, dwB, 5632, ctb,
                                                 (it == 1 ? out : ctf), xb, 2048);
  }
}

// Round 3
// 877.534 us; speedup vs baseline: 1.3940x; 1.0987x over previous
//
#include <hip/hip_runtime.h>

typedef __attribute__((ext_vector_type(8))) short short8;
typedef __attribute__((ext_vector_type(4))) float f32x4;
typedef __attribute__((ext_vector_type(4))) unsigned short us4;

__device__ __forceinline__ unsigned short f2bf(float f) {
  union { float f; unsigned u; } v; v.f = f;
  unsigned r = v.u + 0x7fffu + ((v.u >> 16) & 1u);
  return (unsigned short)(r >> 16);
}
__device__ __forceinline__ float bf2f(unsigned short b) {
  union { unsigned u; float f; } v; v.u = ((unsigned)b) << 16;
  return v.f;
}
__device__ __forceinline__ float fexp2(float x) {
  float r; asm("v_exp_f32 %0, %1" : "=v"(r) : "v"(x)); return r;
}

__device__ __forceinline__ void gload_lds16(const void* g, void* l) {
  __builtin_amdgcn_global_load_lds((const __attribute__((address_space(1))) void*)g,
                                   (__attribute__((address_space(3))) void*)l,
                                   16, 0, 0);
}

#define VMW6() asm volatile("s_waitcnt vmcnt(6)" ::: "memory")
#define VMW0() asm volatile("s_waitcnt vmcnt(0)" ::: "memory")
#define LGKM0() asm volatile("s_waitcnt lgkmcnt(0)" ::: "memory")

// Stage an R x 64 bf16 tile (row-major, 128B rows) into LDS, linear dest,
// inverse-XOR-swizzled global source (rule #21): LDS(row, g16) holds
// global(row, g16 ^ (row&7)) where g16 indexes 16B granules.
template<int R>
__device__ __forceinline__ void stage64(const unsigned short* g, int K, int k0,
                                        unsigned short* lds, int tid) {
  const int lane = tid & 63, w = tid >> 6;
  constexpr int RW = R / 4;   // rows per wave
  constexpr int NL = RW / 8;  // loads per thread
#pragma unroll
  for (int i = 0; i < NL; i++) {
    const int r0 = w * RW + i * 8;
    const int row = r0 + (lane >> 3);
    const int colb = (((lane & 7) ^ (lane >> 3)) << 4);
    gload_lds16((const char*)(g + (size_t)row * K + k0) + colb, lds + r0 * 64);
  }
}

// Swizzled fragment read: returns global(row, cb..cb+15 bytes) of a 128B-row tile.
__device__ __forceinline__ short8 lds_frag(const unsigned short* t, int row, int cb) {
  return *(const short8*)((const char*)t + row * 128 + (cb ^ ((row & 7) << 4)));
}

// ---------------------------------------------------------------------------
// C[M,N] = A[M,K] @ B[N,K]^T  (bf16 in, fp32 accum). BM=64, BN=128, BK=64,
// 3-buffer depth-2 pipeline with counted vmcnt. 4 waves, wave tile 32x64.
// EPI: 0 plain bf16; 1 transposed bf16 (outb[col*ldo+row], pack4);
//      2 silu bf16; 3 out = v*aux; 4 outf[idx] += v;
//      5 t=v+aux; outf=t; outb=bf16(t); 6 bf16(v * qscale)
// ---------------------------------------------------------------------------
template<int EPI>
__global__ __launch_bounds__(256) void gemm_bt(
    const unsigned short* __restrict__ A,
    const unsigned short* __restrict__ B,
    int K,
    unsigned short* __restrict__ outb,
    float* __restrict__ outf,
    const unsigned short* __restrict__ aux,
    int ldo)
{
  constexpr int BM = 64, BN = 128, BK = 64;
  __shared__ __align__(16) unsigned short sA[3][BM * BK];
  __shared__ __align__(16) unsigned short sB[3][BN * BK];
  const int tid = threadIdx.x;
  const int lane = tid & 63, w = tid >> 6;
  const int wr = w >> 1, wc = w & 1;
  const int ln = lane & 15, qo = lane >> 4;
  const size_t m0 = (size_t)blockIdx.y * BM, n0 = (size_t)blockIdx.x * BN;
  const unsigned short* Ab = A + m0 * K;
  const unsigned short* Bb = B + n0 * K;

  const f32x4 z4 = {0.f, 0.f, 0.f, 0.f};
  f32x4 acc[2][4];
#pragma unroll
  for (int i = 0; i < 2; i++)
#pragma unroll
    for (int j = 0; j < 4; j++) acc[i][j] = z4;

  const int nt = K / BK;
  stage64<BM>(Ab, K, 0, sA[0], tid);
  stage64<BN>(Bb, K, 0, sB[0], tid);
  stage64<BM>(Ab, K, BK, sA[1], tid);
  stage64<BN>(Bb, K, BK, sB[1], tid);

  int cur = 0;
  for (int t = 0; t < nt; ++t) {
    if (t == nt - 1) VMW0(); else VMW6();
    __builtin_amdgcn_s_barrier();
    asm volatile("" ::: "memory");
    if (t + 2 < nt) {
      const int nx = (cur == 0) ? 2 : cur - 1;  // (cur+2)%3
      stage64<BM>(Ab, K, (t + 2) * BK, sA[nx], tid);
      stage64<BN>(Bb, K, (t + 2) * BK, sB[nx], tid);
    }
    const unsigned short* cA = sA[cur];
    const unsigned short* cB = sB[cur];
#pragma unroll
    for (int ks = 0; ks < 2; ks++) {
      short8 af[2], bfv[4];
#pragma unroll
      for (int mi = 0; mi < 2; mi++)
        af[mi] = lds_frag(cA, wr * 32 + mi * 16 + ln, ks * 64 + qo * 16);
#pragma unroll
      for (int ni = 0; ni < 4; ni++)
        bfv[ni] = lds_frag(cB, wc * 64 + ni * 16 + ln, ks * 64 + qo * 16);
      __builtin_amdgcn_s_setprio(1);
#pragma unroll
      for (int mi = 0; mi < 2; mi++)
#pragma unroll
        for (int ni = 0; ni < 4; ni++)
          acc[mi][ni] = __builtin_amdgcn_mfma_f32_16x16x32_bf16(af[mi], bfv[ni], acc[mi][ni], 0, 0, 0);
      __builtin_amdgcn_s_setprio(0);
    }
    cur = (cur == 2) ? 0 : cur + 1;
  }

#pragma unroll
  for (int mi = 0; mi < 2; mi++) {
#pragma unroll
    for (int ni = 0; ni < 4; ni++) {
      const size_t row4 = m0 + wr * 32 + mi * 16 + qo * 4;
      const size_t col  = n0 + wc * 64 + ni * 16 + ln;
      if (EPI == 1) {
        us4 pk;
        pk[0] = f2bf(acc[mi][ni][0]); pk[1] = f2bf(acc[mi][ni][1]);
        pk[2] = f2bf(acc[mi][ni][2]); pk[3] = f2bf(acc[mi][ni][3]);
        *(us4*)&outb[col * (size_t)ldo + row4] = pk;
      } else {
#pragma unroll
        for (int r = 0; r < 4; r++) {
          const size_t idx = (row4 + r) * (size_t)ldo + col;
          float v = acc[mi][ni][r];
          if (EPI == 0) outb[idx] = f2bf(v);
          if (EPI == 2) outb[idx] = f2bf(v / (1.f + __expf(-v)));
          if (EPI == 3) outb[idx] = f2bf(v * bf2f(aux[idx]));
          if (EPI == 4) outf[idx] += v;
          if (EPI == 5) { float t = v + bf2f(aux[idx]); outf[idx] = t; outb[idx] = f2bf(t); }
          if (EPI == 6) outb[idx] = f2bf(v * 0.18033688011112042f);  // 2^-3 * log2(e)
        }
      }
    }
  }
}

// ---------------------------------------------------------------------------
// Flash attention. Grid: (16 q-blocks of 64, 32 heads) = 512 blocks, 4 waves.
// Wave owns 16 q rows. KV tiles of 64 keys, double-buffered via
// global_load_lds with XOR-swizzled source. Swapped QK^T (S^T = mfma(K,Q)):
// lane holds S[key][q=ln]; softmax reduce = 16 in-lane + shfl_xor(16,32).
// P is wave-private (no barrier), swizzled in LDS. Q pre-scaled by
// 0.125*log2e so P = exp2(S - m) directly.
// ---------------------------------------------------------------------------
__global__ __launch_bounds__(256) void attn_k(
    const unsigned short* __restrict__ Q,   // 1024 x 2048 (pre-scaled)
    const unsigned short* __restrict__ Kb,  // 3072 x 512
    const unsigned short* __restrict__ Vt,  // 512 x 3072
    unsigned short* __restrict__ O)         // 1024 x 2048
{
  __shared__ __align__(16) unsigned short sK[2][64 * 64];
  __shared__ __align__(16) unsigned short sV[2][64 * 64];
  __shared__ __align__(16) unsigned short sP[64 * 64];
  const int tid = threadIdx.x;
  const int lane = tid & 63, w = tid >> 6;
  const int ln = lane & 15, qo = lane >> 4;
  const int head = blockIdx.y, kvh = head >> 2;
  const int qw = blockIdx.x * 64 + w * 16;

  // Q fragments (B-operand): lane holds Q[q=qw+ln][hd kc*32+qo*8 ..+7]
  short8 qf[2];
  qf[0] = *(const short8*)&Q[(size_t)(qw + ln) * 2048 + head * 64 + qo * 8];
  qf[1] = *(const short8*)&Q[(size_t)(qw + ln) * 2048 + head * 64 + 32 + qo * 8];

  const f32x4 z4 = {0.f, 0.f, 0.f, 0.f};
  f32x4 oacc[4] = {z4, z4, z4, z4};
  float mrun = -1e30f, lrun = 0.f;

  const unsigned short* Kg = Kb + kvh * 64;                 // row stride 512
  const unsigned short* Vg = Vt + (size_t)(kvh * 64) * 3072; // row stride 3072

  stage64<64>(Kg, 512, 0, sK[0], tid);
  stage64<64>(Vg, 3072, 0, sV[0], tid);

  for (int t = 0; t < 48; ++t) {
    const int cur = t & 1;
    VMW0();
    __builtin_amdgcn_s_barrier();
    asm volatile("" ::: "memory");
    if (t + 1 < 48) {
      stage64<64>(Kg + (size_t)(t + 1) * 64 * 512, 512, 0, sK[cur ^ 1], tid);
      stage64<64>(Vg, 3072, (t + 1) * 64, sV[cur ^ 1], tid);
    }

    // QK^T: S^T[key][q]
    f32x4 sacc[4] = {z4, z4, z4, z4};
#pragma unroll
    for (int kc = 0; kc < 2; kc++) {
      short8 kf[4];
#pragma unroll
      for (int mi = 0; mi < 4; mi++)
        kf[mi] = lds_frag(sK[cur], mi * 16 + ln, kc * 64 + qo * 16);
      __builtin_amdgcn_s_setprio(1);
#pragma unroll
      for (int mi = 0; mi < 4; mi++)
        sacc[mi] = __builtin_amdgcn_mfma_f32_16x16x32_bf16(kf[mi], qf[kc], sacc[mi], 0, 0, 0);
      __builtin_amdgcn_s_setprio(0);
    }

    // online softmax for q = ln (keys: 16*mi + 4*qo + r, spread over qo via shfl)
    float tm = -1e30f;
#pragma unroll
    for (int mi = 0; mi < 4; mi++) {
      float a0 = fmaxf(sacc[mi][0], sacc[mi][1]);
      float a1 = fmaxf(sacc[mi][2], sacc[mi][3]);
      tm = fmaxf(tm, fmaxf(a0, a1));
    }
    tm = fmaxf(tm, __shfl_xor(tm, 16));
    tm = fmaxf(tm, __shfl_xor(tm, 32));
    const float mn = fmaxf(mrun, tm);
    const float al = fexp2(mrun - mn);
    float ts = 0.f;
#pragma unroll
    for (int mi = 0; mi < 4; mi++) {
      us4 pk;
#pragma unroll
      for (int r = 0; r < 4; r++) {
        float pv = fexp2(sacc[mi][r] - mn);
        ts += pv;
        pk[r] = f2bf(pv);
      }
      // P[q=qw-local row][keys 16mi+4qo .. +3], swizzled 8B write
      const int row = w * 16 + ln;
      const int g16 = (2 * mi + (qo >> 1)) ^ (ln & 7);
      *(us4*)((char*)sP + row * 128 + (g16 << 4) + ((qo & 1) << 3)) = pk;
    }
    ts += __shfl_xor(ts, 16);
    ts += __shfl_xor(ts, 32);
    lrun = lrun * al + ts;
    mrun = mn;

    // rescale O (rows q = 4*qo + r)
#pragma unroll
    for (int r = 0; r < 4; r++) {
      float ar = __shfl(al, qo * 4 + r);
#pragma unroll
      for (int ni = 0; ni < 4; ni++) oacc[ni][r] *= ar;
    }

    // PV: O[q][hd] += P[q][keys] * V[keys][hd]
#pragma unroll
    for (int ks = 0; ks < 2; ks++) {
      short8 pf = lds_frag(sP, w * 16 + ln, ks * 64 + qo * 16);
      short8 vf[4];
#pragma unroll
      for (int ni = 0; ni < 4; ni++)
        vf[ni] = lds_frag(sV[cur], ni * 16 + ln, ks * 64 + qo * 16);
      __builtin_amdgcn_s_setprio(1);
#pragma unroll
      for (int ni = 0; ni < 4; ni++)
        oacc[ni] = __builtin_amdgcn_mfma_f32_16x16x32_bf16(pf, vf[ni], oacc[ni], 0, 0, 0);
      __builtin_amdgcn_s_setprio(0);
    }
    LGKM0();
  }

  const float linv = 1.f / lrun;
#pragma unroll
  for (int r = 0; r < 4; r++) {
    float lr = __shfl(linv, qo * 4 + r);
#pragma unroll
    for (int ni = 0; ni < 4; ni++)
      O[(size_t)(qw + qo * 4 + r) * 2048 + head * 64 + ni * 16 + ln] =
          f2bf(oacc[ni][r] * lr);
  }
}

// ---------------------------------------------------------------------------
__global__ __launch_bounds__(256) void rmsnorm_k(const float* __restrict__ in,
                                                 const float* __restrict__ w,
                                                 unsigned short* __restrict__ out) {
  const int row = blockIdx.x;
  const int tid = threadIdx.x;
  const float* x = in + (size_t)row * 2048;
  float4 a = ((const float4*)x)[tid * 2];
  float4 b = ((const float4*)x)[tid * 2 + 1];
  float ss = a.x * a.x + a.y * a.y + a.z * a.z + a.w * a.w +
             b.x * b.x + b.y * b.y + b.z * b.z + b.w * b.w;
#pragma unroll
  for (int d = 1; d < 64; d <<= 1) ss += __shfl_xor(ss, d);
  __shared__ float red[4];
  if ((tid & 63) == 0) red[tid >> 6] = ss;
  __syncthreads();
  float sc = rsqrtf((red[0] + red[1] + red[2] + red[3]) * (1.f / 2048.f) + 1e-6f);
  float4 wa = ((const float4*)w)[tid * 2];
  float4 wb = ((const float4*)w)[tid * 2 + 1];
  us4 o1, o2;
  o1[0] = f2bf(a.x * sc * wa.x); o1[1] = f2bf(a.y * sc * wa.y);
  o1[2] = f2bf(a.z * sc * wa.z); o1[3] = f2bf(a.w * sc * wa.w);
  o2[0] = f2bf(b.x * sc * wb.x); o2[1] = f2bf(b.y * sc * wb.y);
  o2[2] = f2bf(b.z * sc * wb.z); o2[3] = f2bf(b.w * sc * wb.w);
  us4* op = (us4*)&out[(size_t)row * 2048 + tid * 8];
  op[0] = o1; op[1] = o2;
}

__global__ __launch_bounds__(256) void cvt_k(const float* __restrict__ in,
                                             unsigned short* __restrict__ out, int n4) {
  int i = blockIdx.x * 256 + threadIdx.x;
  const int stride = gridDim.x * 256;
  for (; i < n4; i += stride) {
    float4 v = ((const float4*)in)[i];
    us4 o;
    o[0] = f2bf(v.x); o[1] = f2bf(v.y); o[2] = f2bf(v.z); o[3] = f2bf(v.w);
    ((us4*)out)[i] = o;
  }
}

__global__ __launch_bounds__(256) void initct_k(const float* __restrict__ hidden,
                                                float* __restrict__ ctf,
                                                unsigned short* __restrict__ ctb) {
  int i = blockIdx.x * 256 + threadIdx.x;
  const int stride = gridDim.x * 256;
  for (; i < 524288; i += stride) {
    float4 v = ((const float4*)hidden)[524288 + i];
    ((float4*)ctf)[i] = v;
    us4 o;
    o[0] = f2bf(v.x); o[1] = f2bf(v.y); o[2] = f2bf(v.z); o[3] = f2bf(v.w);
    ((us4*)ctb)[i] = o;
  }
}

// ---------------------------------------------------------------------------
extern "C" void kernel_launch(void* const* d_in, const int* in_sizes, int n_in,
                              void* d_out, int out_size, void* d_ws, size_t ws_size,
                              hipStream_t stream) {
  (void)in_sizes; (void)n_in; (void)out_size; (void)ws_size;
  const float* hidden = (const float*)d_in[0];
  const float* q_w  = (const float*)d_in[1];
  const float* k_w  = (const float*)d_in[2];
  const float* v_w  = (const float*)d_in[3];
  const float* o_w  = (const float*)d_in[4];
  const float* a_nw = (const float*)d_in[5];
  const float* m_nw = (const float*)d_in[6];
  const float* g_w  = (const float*)d_in[7];
  const float* u_w  = (const float*)d_in[8];
  const float* dn_w = (const float*)d_in[9];
  float* out = (float*)d_out;

  char* p = (char*)d_ws;
  size_t off = 0;
  auto take = [&](size_t bytes) -> char* {
    char* r = p + off;
    off += (bytes + 255) & ~(size_t)255;
    return r;
  };
  float* ctf          = (float*)take((size_t)1024 * 2048 * 4);
  unsigned short* ctb = (unsigned short*)take((size_t)1024 * 2048 * 2);
  unsigned short* xb  = (unsigned short*)take((size_t)1024 * 2048 * 2);
  unsigned short* hb  = (unsigned short*)take((size_t)2048 * 2048 * 2);
  unsigned short* qwB = (unsigned short*)take((size_t)2048 * 2048 * 2);
  unsigned short* kwB = (unsigned short*)take((size_t)512 * 2048 * 2);
  unsigned short* vwB = (unsigned short*)take((size_t)512 * 2048 * 2);
  unsigned short* owB = (unsigned short*)take((size_t)2048 * 2048 * 2);
  unsigned short* gwB = (unsigned short*)take((size_t)5632 * 2048 * 2);
  unsigned short* uwB = (unsigned short*)take((size_t)5632 * 2048 * 2);
  unsigned short* dwB = (unsigned short*)take((size_t)2048 * 5632 * 2);
  unsigned short* qB  = (unsigned short*)take((size_t)1024 * 2048 * 2);
  unsigned short* kB  = (unsigned short*)take((size_t)3072 * 512 * 2);
  unsigned short* vtB = (unsigned short*)take((size_t)512 * 3072 * 2);
  unsigned short* oB  = (unsigned short*)take((size_t)1024 * 2048 * 2);
  unsigned short* gtB = (unsigned short*)take((size_t)1024 * 5632 * 2);

  dim3 blk(256);
  auto cvt = [&](const float* src, unsigned short* dst, size_t n) {
    int n4 = (int)(n / 4);
    int g = (n4 + 255) / 256; if (g > 1024) g = 1024;
    cvt_k<<<dim3(g), blk, 0, stream>>>(src, dst, n4);
  };
  cvt(q_w, qwB, (size_t)2048 * 2048);
  cvt(k_w, kwB, (size_t)512 * 2048);
  cvt(v_w, vwB, (size_t)512 * 2048);
  cvt(o_w, owB, (size_t)2048 * 2048);
  cvt(g_w, gwB, (size_t)5632 * 2048);
  cvt(u_w, uwB, (size_t)5632 * 2048);
  cvt(dn_w, dwB, (size_t)2048 * 5632);
  cvt(hidden, hb, (size_t)2048 * 2048);
  initct_k<<<dim3(1024), blk, 0, stream>>>(hidden, ctf, ctb);

  // K/V of the fixed hidden prefix (rows 0..2047): identical both layers
  gemm_bt<0><<<dim3(4, 32), blk, 0, stream>>>(hb, kwB, 2048, kB, nullptr, nullptr, 512);
  gemm_bt<1><<<dim3(4, 32), blk, 0, stream>>>(hb, vwB, 2048, vtB, nullptr, nullptr, 3072);

  for (int it = 0; it < 2; it++) {
    rmsnorm_k<<<dim3(1024), blk, 0, stream>>>(ctf, a_nw, xb);
    gemm_bt<6><<<dim3(16, 16), blk, 0, stream>>>(xb, qwB, 2048, qB, nullptr, nullptr, 2048);
    gemm_bt<0><<<dim3(4, 16), blk, 0, stream>>>(ctb, kwB, 2048, kB + (size_t)2048 * 512, nullptr, nullptr, 512);
    gemm_bt<1><<<dim3(4, 16), blk, 0, stream>>>(ctb, vwB, 2048, vtB + 2048, nullptr, nullptr, 3072);
    attn_k<<<dim3(16, 32), blk, 0, stream>>>(qB, kB, vtB, oB);
    gemm_bt<4><<<dim3(16, 16), blk, 0, stream>>>(oB, owB, 2048, nullptr, ctf, nullptr, 2048);
    rmsnorm_k<<<dim3(1024), blk, 0, stream>>>(ctf, m_nw, xb);
    gemm_bt<2><<<dim3(44, 16), blk, 0, stream>>>(xb, gwB, 2048, gtB, nullptr, nullptr, 5632);
    gemm_bt<3><<<dim3(44, 16), blk, 0, stream>>>(xb, uwB, 2048, gtB, nullptr, gtB, 5632);
    gemm_bt<5><<<dim3(16, 16), blk, 0, stream>>>(gtB, dwB, 5632, ctb,
                                                 (it == 1 ? out : ctf), xb, 2048);
  }
}

// Round 4
// 695.260 us; speedup vs baseline: 1.7594x; 1.2622x over previous
//
#include <hip/hip_runtime.h>

typedef __attribute__((ext_vector_type(8))) short short8;
typedef __attribute__((ext_vector_type(4))) float f32x4;
typedef __attribute__((ext_vector_type(4))) unsigned short us4;

__device__ __forceinline__ unsigned short f2bf(float f) {
  union { float f; unsigned u; } v; v.f = f;
  unsigned r = v.u + 0x7fffu + ((v.u >> 16) & 1u);
  return (unsigned short)(r >> 16);
}
__device__ __forceinline__ float bf2f(unsigned short b) {
  union { unsigned u; float f; } v; v.u = ((unsigned)b) << 16;
  return v.f;
}
__device__ __forceinline__ float fexp2(float x) {
  float r; asm("v_exp_f32 %0, %1" : "=v"(r) : "v"(x)); return r;
}

__device__ __forceinline__ void gload_lds16(const void* g, void* l) {
  __builtin_amdgcn_global_load_lds((const __attribute__((address_space(1))) void*)g,
                                   (__attribute__((address_space(3))) void*)l,
                                   16, 0, 0);
}

#define VMW6() asm volatile("s_waitcnt vmcnt(6)" ::: "memory")
#define VMW0() asm volatile("s_waitcnt vmcnt(0)" ::: "memory")
#define LGKM0() asm volatile("s_waitcnt lgkmcnt(0)" ::: "memory")

// Stage an R x 64 bf16 tile (row-major, 128B rows) into LDS, linear dest,
// inverse-XOR-swizzled global source: LDS(row, g16) holds global(row, g16^(row&7)).
template<int R>
__device__ __forceinline__ void stage64(const unsigned short* g, int K, int k0,
                                        unsigned short* lds, int tid) {
  const int lane = tid & 63, w = tid >> 6;
  constexpr int RW = R / 4;
  constexpr int NL = RW / 8;
#pragma unroll
  for (int i = 0; i < NL; i++) {
    const int r0 = w * RW + i * 8;
    const int row = r0 + (lane >> 3);
    const int colb = (((lane & 7) ^ (lane >> 3)) << 4);
    gload_lds16((const char*)(g + (size_t)row * K + k0) + colb, lds + r0 * 64);
  }
}

// Swizzled fragment read from a 128B-row tile.
__device__ __forceinline__ short8 lds_frag(const unsigned short* t, int row, int cb) {
  return *(const short8*)((const char*)t + row * 128 + (cb ^ ((row & 7) << 4)));
}

// ---------------------------------------------------------------------------
// Single-B GEMM: C[M,N] = A[M,K] @ B[N,K]^T. BM=64, BN=128, BK=64, 3-buffer
// depth-2, counted vmcnt. EPI: 0 plain bf16; 4 outf[idx]+=v;
// 5 t=v+aux -> outf=t, outb=bf16(t); 6 bf16(v*qscale)
// ---------------------------------------------------------------------------
template<int EPI>
__global__ __launch_bounds__(256) void gemm_bt(
    const unsigned short* __restrict__ A,
    const unsigned short* __restrict__ B,
    int K,
    unsigned short* __restrict__ outb,
    float* __restrict__ outf,
    const unsigned short* __restrict__ aux,
    int ldo)
{
  constexpr int BM = 64, BN = 128, BK = 64;
  __shared__ __align__(16) unsigned short sA[3][BM * BK];
  __shared__ __align__(16) unsigned short sB[3][BN * BK];
  const int tid = threadIdx.x;
  const int lane = tid & 63, w = tid >> 6;
  const int wr = w >> 1, wc = w & 1;
  const int ln = lane & 15, qo = lane >> 4;
  const size_t m0 = (size_t)blockIdx.y * BM, n0 = (size_t)blockIdx.x * BN;
  const unsigned short* Ab = A + m0 * K;
  const unsigned short* Bb = B + n0 * K;

  const f32x4 z4 = {0.f, 0.f, 0.f, 0.f};
  f32x4 acc[2][4];
#pragma unroll
  for (int i = 0; i < 2; i++)
#pragma unroll
    for (int j = 0; j < 4; j++) acc[i][j] = z4;

  const int nt = K / BK;
  stage64<BM>(Ab, K, 0, sA[0], tid);
  stage64<BN>(Bb, K, 0, sB[0], tid);
  stage64<BM>(Ab, K, BK, sA[1], tid);
  stage64<BN>(Bb, K, BK, sB[1], tid);

  int cur = 0;
  for (int t = 0; t < nt; ++t) {
    if (t == nt - 1) VMW0(); else VMW6();
    __builtin_amdgcn_s_barrier();
    asm volatile("" ::: "memory");
    if (t + 2 < nt) {
      const int nx = (cur == 0) ? 2 : cur - 1;
      stage64<BM>(Ab, K, (t + 2) * BK, sA[nx], tid);
      stage64<BN>(Bb, K, (t + 2) * BK, sB[nx], tid);
    }
    const unsigned short* cA = sA[cur];
    const unsigned short* cB = sB[cur];
#pragma unroll
    for (int ks = 0; ks < 2; ks++) {
      short8 af[2], bfv[4];
#pragma unroll
      for (int mi = 0; mi < 2; mi++)
        af[mi] = lds_frag(cA, wr * 32 + mi * 16 + ln, ks * 64 + qo * 16);
#pragma unroll
      for (int ni = 0; ni < 4; ni++)
        bfv[ni] = lds_frag(cB, wc * 64 + ni * 16 + ln, ks * 64 + qo * 16);
      __builtin_amdgcn_s_setprio(1);
#pragma unroll
      for (int mi = 0; mi < 2; mi++)
#pragma unroll
        for (int ni = 0; ni < 4; ni++)
          acc[mi][ni] = __builtin_amdgcn_mfma_f32_16x16x32_bf16(af[mi], bfv[ni], acc[mi][ni], 0, 0, 0);
      __builtin_amdgcn_s_setprio(0);
    }
    cur = (cur == 2) ? 0 : cur + 1;
  }

#pragma unroll
  for (int mi = 0; mi < 2; mi++) {
#pragma unroll
    for (int ni = 0; ni < 4; ni++) {
      const size_t row4 = m0 + wr * 32 + mi * 16 + qo * 4;
      const size_t col  = n0 + wc * 64 + ni * 16 + ln;
#pragma unroll
      for (int r = 0; r < 4; r++) {
        const size_t idx = (row4 + r) * (size_t)ldo + col;
        float v = acc[mi][ni][r];
        if (EPI == 0) outb[idx] = f2bf(v);
        if (EPI == 4) outf[idx] += v;
        if (EPI == 5) { float t = v + bf2f(aux[idx]); outf[idx] = t; outb[idx] = f2bf(t); }
        if (EPI == 6) outb[idx] = f2bf(v * 0.18033688011112042f);  // 2^-3 * log2(e)
      }
    }
  }
}

// ---------------------------------------------------------------------------
// Dual-B GEMM: shares A, computes C0 = A@B0^T and C1 = A@B1^T. BM=64, BN=64
// (each), BK=64, 3-buffer depth-2, vmcnt(6). Wave tile 32x32 per output.
// MODE 0 (KV): out0 bf16 row-major ld0; out1 bf16 transposed (out1[col*ld1+row]).
// MODE 1 (GU): out0 = bf16(silu(c0)*c1) row-major ld0.
// ---------------------------------------------------------------------------
template<int MODE>
__global__ __launch_bounds__(256) void gemm_dual(
    const unsigned short* __restrict__ A,
    const unsigned short* __restrict__ B0,
    const unsigned short* __restrict__ B1,
    int K,
    unsigned short* __restrict__ out0,
    unsigned short* __restrict__ out1,
    int ld0, int ld1)
{
  constexpr int BM = 64, BN = 64, BK = 64;
  __shared__ __align__(16) unsigned short sA[3][BM * BK];
  __shared__ __align__(16) unsigned short sB0[3][BN * BK];
  __shared__ __align__(16) unsigned short sB1[3][BN * BK];
  const int tid = threadIdx.x;
  const int lane = tid & 63, w = tid >> 6;
  const int wr = w >> 1, wc = w & 1;
  const int ln = lane & 15, qo = lane >> 4;
  const size_t m0 = (size_t)blockIdx.y * BM, n0 = (size_t)blockIdx.x * BN;
  const unsigned short* Ab = A + m0 * K;
  const unsigned short* B0b = B0 + n0 * K;
  const unsigned short* B1b = B1 + n0 * K;

  const f32x4 z4 = {0.f, 0.f, 0.f, 0.f};
  f32x4 acc0[2][2], acc1[2][2];
#pragma unroll
  for (int i = 0; i < 2; i++)
#pragma unroll
    for (int j = 0; j < 2; j++) { acc0[i][j] = z4; acc1[i][j] = z4; }

  const int nt = K / BK;
  stage64<BM>(Ab, K, 0, sA[0], tid);
  stage64<BN>(B0b, K, 0, sB0[0], tid);
  stage64<BN>(B1b, K, 0, sB1[0], tid);
  stage64<BM>(Ab, K, BK, sA[1], tid);
  stage64<BN>(B0b, K, BK, sB0[1], tid);
  stage64<BN>(B1b, K, BK, sB1[1], tid);

  int cur = 0;
  for (int t = 0; t < nt; ++t) {
    if (t == nt - 1) VMW0(); else VMW6();
    __builtin_amdgcn_s_barrier();
    asm volatile("" ::: "memory");
    if (t + 2 < nt) {
      const int nx = (cur == 0) ? 2 : cur - 1;
      stage64<BM>(Ab, K, (t + 2) * BK, sA[nx], tid);
      stage64<BN>(B0b, K, (t + 2) * BK, sB0[nx], tid);
      stage64<BN>(B1b, K, (t + 2) * BK, sB1[nx], tid);
    }
    const unsigned short* cA = sA[cur];
    const unsigned short* cB0 = sB0[cur];
    const unsigned short* cB1 = sB1[cur];
#pragma unroll
    for (int ks = 0; ks < 2; ks++) {
      short8 af[2], b0f[2], b1f[2];
#pragma unroll
      for (int mi = 0; mi < 2; mi++)
        af[mi] = lds_frag(cA, wr * 32 + mi * 16 + ln, ks * 64 + qo * 16);
#pragma unroll
      for (int ni = 0; ni < 2; ni++) {
        b0f[ni] = lds_frag(cB0, wc * 32 + ni * 16 + ln, ks * 64 + qo * 16);
        b1f[ni] = lds_frag(cB1, wc * 32 + ni * 16 + ln, ks * 64 + qo * 16);
      }
      __builtin_amdgcn_s_setprio(1);
#pragma unroll
      for (int mi = 0; mi < 2; mi++)
#pragma unroll
        for (int ni = 0; ni < 2; ni++) {
          acc0[mi][ni] = __builtin_amdgcn_mfma_f32_16x16x32_bf16(af[mi], b0f[ni], acc0[mi][ni], 0, 0, 0);
          acc1[mi][ni] = __builtin_amdgcn_mfma_f32_16x16x32_bf16(af[mi], b1f[ni], acc1[mi][ni], 0, 0, 0);
        }
      __builtin_amdgcn_s_setprio(0);
    }
    cur = (cur == 2) ? 0 : cur + 1;
  }

#pragma unroll
  for (int mi = 0; mi < 2; mi++) {
#pragma unroll
    for (int ni = 0; ni < 2; ni++) {
      const size_t row4 = m0 + wr * 32 + mi * 16 + qo * 4;
      const size_t col  = n0 + wc * 32 + ni * 16 + ln;
      if (MODE == 0) {
#pragma unroll
        for (int r = 0; r < 4; r++)
          out0[(row4 + r) * (size_t)ld0 + col] = f2bf(acc0[mi][ni][r]);
        us4 pk;
        pk[0] = f2bf(acc1[mi][ni][0]); pk[1] = f2bf(acc1[mi][ni][1]);
        pk[2] = f2bf(acc1[mi][ni][2]); pk[3] = f2bf(acc1[mi][ni][3]);
        *(us4*)&out1[col * (size_t)ld1 + row4] = pk;
      } else {
#pragma unroll
        for (int r = 0; r < 4; r++) {
          float g = acc0[mi][ni][r], u = acc1[mi][ni][r];
          out0[(row4 + r) * (size_t)ld0 + col] = f2bf(g / (1.f + __expf(-g)) * u);
        }
      }
    }
  }
}

// ---------------------------------------------------------------------------
// Flash attention, split-KV by 2. Grid (16 q-blocks of 64, 32 heads, 2 halves)
// = 1024 blocks, 4 waves, LDS 40KB -> 4 blocks/CU. Each block does 24 of the
// 48 KV tiles, writes UNNORMALIZED partial O (bf16) and per-row (m,l).
// Swapped QK^T; Q pre-scaled by 0.125*log2e; defer-rescale THR=11 (log2).
// ---------------------------------------------------------------------------
__global__ __launch_bounds__(256) void attn_k(
    const unsigned short* __restrict__ Q,   // 1024 x 2048 (pre-scaled)
    const unsigned short* __restrict__ Kb,  // 3072 x 512
    const unsigned short* __restrict__ Vt,  // 512 x 3072
    unsigned short* __restrict__ Op,        // [2][1024][2048] bf16 partials
    float* __restrict__ Ml)                 // [2][32][1024][2]
{
  __shared__ __align__(16) unsigned short sK[2][64 * 64];
  __shared__ __align__(16) unsigned short sV[2][64 * 64];
  __shared__ __align__(16) unsigned short sP[64 * 64];
  const int tid = threadIdx.x;
  const int lane = tid & 63, w = tid >> 6;
  const int ln = lane & 15, qo = lane >> 4;
  const int head = blockIdx.y, kvh = head >> 2;
  const int half = blockIdx.z;
  const int qw = blockIdx.x * 64 + w * 16;
  const int key0 = half * 1536;

  short8 qf[2];
  qf[0] = *(const short8*)&Q[(size_t)(qw + ln) * 2048 + head * 64 + qo * 8];
  qf[1] = *(const short8*)&Q[(size_t)(qw + ln) * 2048 + head * 64 + 32 + qo * 8];

  const f32x4 z4 = {0.f, 0.f, 0.f, 0.f};
  f32x4 oacc[4] = {z4, z4, z4, z4};
  float mrun = -1e30f, lrun = 0.f;

  const unsigned short* Kg = Kb + kvh * 64;
  const unsigned short* Vg = Vt + (size_t)(kvh * 64) * 3072;

  stage64<64>(Kg + (size_t)key0 * 512, 512, 0, sK[0], tid);
  stage64<64>(Vg, 3072, key0, sV[0], tid);

  for (int t = 0; t < 24; ++t) {
    const int cur = t & 1;
    VMW0();
    __builtin_amdgcn_s_barrier();
    asm volatile("" ::: "memory");
    if (t + 1 < 24) {
      stage64<64>(Kg + (size_t)(key0 + (t + 1) * 64) * 512, 512, 0, sK[cur ^ 1], tid);
      stage64<64>(Vg, 3072, key0 + (t + 1) * 64, sV[cur ^ 1], tid);
    }

    // QK^T: S^T[key][q]
    f32x4 sacc[4] = {z4, z4, z4, z4};
#pragma unroll
    for (int kc = 0; kc < 2; kc++) {
      short8 kf[4];
#pragma unroll
      for (int mi = 0; mi < 4; mi++)
        kf[mi] = lds_frag(sK[cur], mi * 16 + ln, kc * 64 + qo * 16);
      __builtin_amdgcn_s_setprio(1);
#pragma unroll
      for (int mi = 0; mi < 4; mi++)
        sacc[mi] = __builtin_amdgcn_mfma_f32_16x16x32_bf16(kf[mi], qf[kc], sacc[mi], 0, 0, 0);
      __builtin_amdgcn_s_setprio(0);
    }

    // online softmax for q = ln
    float tm = -1e30f;
#pragma unroll
    for (int mi = 0; mi < 4; mi++) {
      float a0 = fmaxf(sacc[mi][0], sacc[mi][1]);
      float a1 = fmaxf(sacc[mi][2], sacc[mi][3]);
      tm = fmaxf(tm, fmaxf(a0, a1));
    }
    tm = fmaxf(tm, __shfl_xor(tm, 16));
    tm = fmaxf(tm, __shfl_xor(tm, 32));

    if (!__all(tm <= mrun + 11.f)) {  // defer-rescale
      const float mn = fmaxf(mrun, tm);
      const float al = fexp2(mrun - mn);
      lrun *= al;
      mrun = mn;
#pragma unroll
      for (int r = 0; r < 4; r++) {
        float ar = __shfl(al, qo * 4 + r);
#pragma unroll
        for (int ni = 0; ni < 4; ni++) oacc[ni][r] *= ar;
      }
    }

    float ts = 0.f;
#pragma unroll
    for (int mi = 0; mi < 4; mi++) {
      us4 pk;
#pragma unroll
      for (int r = 0; r < 4; r++) {
        float pv = fexp2(sacc[mi][r] - mrun);
        ts += pv;
        pk[r] = f2bf(pv);
      }
      const int row = w * 16 + ln;
      const int g16 = (2 * mi + (qo >> 1)) ^ (ln & 7);
      *(us4*)((char*)sP + row * 128 + (g16 << 4) + ((qo & 1) << 3)) = pk;
    }
    ts += __shfl_xor(ts, 16);
    ts += __shfl_xor(ts, 32);
    lrun += ts;

    // PV
#pragma unroll
    for (int ks = 0; ks < 2; ks++) {
      short8 pf = lds_frag(sP, w * 16 + ln, ks * 64 + qo * 16);
      short8 vf[4];
#pragma unroll
      for (int ni = 0; ni < 4; ni++)
        vf[ni] = lds_frag(sV[cur], ni * 16 + ln, ks * 64 + qo * 16);
      __builtin_amdgcn_s_setprio(1);
#pragma unroll
      for (int ni = 0; ni < 4; ni++)
        oacc[ni] = __builtin_amdgcn_mfma_f32_16x16x32_bf16(pf, vf[ni], oacc[ni], 0, 0, 0);
      __builtin_amdgcn_s_setprio(0);
    }
    LGKM0();
  }

  // write unnormalized partials + (m, l)
  if (qo == 0)
    *(float2*)&Ml[((size_t)(half * 32 + head) * 1024 + qw + ln) * 2] =
        make_float2(mrun, lrun);
#pragma unroll
  for (int r = 0; r < 4; r++)
#pragma unroll
    for (int ni = 0; ni < 4; ni++)
      Op[(size_t)half * 2097152 + (size_t)(qw + qo * 4 + r) * 2048 + head * 64 + ni * 16 + ln] =
          f2bf(oacc[ni][r]);
}

// Combine the two split-KV halves into oB.
__global__ __launch_bounds__(256) void attn_combine(
    const unsigned short* __restrict__ Op,
    const float* __restrict__ Ml,
    unsigned short* __restrict__ O)
{
  const int f = blockIdx.x * 256 + threadIdx.x;   // 0 .. 524287
  const int q = f >> 9;
  const int c = (f & 511) * 4;
  const int head = c >> 6;
  const float2 ml0 = *(const float2*)&Ml[((size_t)head * 1024 + q) * 2];
  const float2 ml1 = *(const float2*)&Ml[((size_t)(32 + head) * 1024 + q) * 2];
  const float m = fmaxf(ml0.x, ml1.x);
  const float w0 = fexp2(ml0.x - m), w1 = fexp2(ml1.x - m);
  const float inv = 1.f / (w0 * ml0.y + w1 * ml1.y);
  const us4 o0 = *(const us4*)&Op[(size_t)q * 2048 + c];
  const us4 o1 = *(const us4*)&Op[2097152 + (size_t)q * 2048 + c];
  us4 o;
#pragma unroll
  for (int j = 0; j < 4; j++)
    o[j] = f2bf((w0 * bf2f(o0[j]) + w1 * bf2f(o1[j])) * inv);
  *(us4*)&O[(size_t)q * 2048 + c] = o;
}

// ---------------------------------------------------------------------------
__global__ __launch_bounds__(256) void rmsnorm_k(const float* __restrict__ in,
                                                 const float* __restrict__ w,
                                                 unsigned short* __restrict__ out) {
  const int row = blockIdx.x;
  const int tid = threadIdx.x;
  const float* x = in + (size_t)row * 2048;
  float4 a = ((const float4*)x)[tid * 2];
  float4 b = ((const float4*)x)[tid * 2 + 1];
  float ss = a.x * a.x + a.y * a.y + a.z * a.z + a.w * a.w +
             b.x * b.x + b.y * b.y + b.z * b.z + b.w * b.w;
#pragma unroll
  for (int d = 1; d < 64; d <<= 1) ss += __shfl_xor(ss, d);
  __shared__ float red[4];
  if ((tid & 63) == 0) red[tid >> 6] = ss;
  __syncthreads();
  float sc = rsqrtf((red[0] + red[1] + red[2] + red[3]) * (1.f / 2048.f) + 1e-6f);
  float4 wa = ((const float4*)w)[tid * 2];
  float4 wb = ((const float4*)w)[tid * 2 + 1];
  us4 o1, o2;
  o1[0] = f2bf(a.x * sc * wa.x); o1[1] = f2bf(a.y * sc * wa.y);
  o1[2] = f2bf(a.z * sc * wa.z); o1[3] = f2bf(a.w * sc * wa.w);
  o2[0] = f2bf(b.x * sc * wb.x); o2[1] = f2bf(b.y * sc * wb.y);
  o2[2] = f2bf(b.z * sc * wb.z); o2[3] = f2bf(b.w * sc * wb.w);
  us4* op = (us4*)&out[(size_t)row * 2048 + tid * 8];
  op[0] = o1; op[1] = o2;
}

// One kernel converting all 8 fp32->bf16 buffers (segment table in registers).
__global__ __launch_bounds__(256) void cvt8_k(
    const float* __restrict__ s0, const float* __restrict__ s1,
    const float* __restrict__ s2, const float* __restrict__ s3,
    const float* __restrict__ s4, const float* __restrict__ s5,
    const float* __restrict__ s6, const float* __restrict__ s7,
    unsigned short* __restrict__ d0, unsigned short* __restrict__ d1,
    unsigned short* __restrict__ d2, unsigned short* __restrict__ d3,
    unsigned short* __restrict__ d4, unsigned short* __restrict__ d5,
    unsigned short* __restrict__ d6, unsigned short* __restrict__ d7)
{
  // float4 prefix ends
  const int e0 = 1048576, e1 = 2097152, e2 = 2359296, e3 = 2621440,
            e4 = 3670016, e5 = 6553600, e6 = 9437184, e7 = 12320768;
  int i = blockIdx.x * 256 + threadIdx.x;
  const int stride = gridDim.x * 256;
  for (; i < e7; i += stride) {
    const float* s; unsigned short* d; int j;
    if (i < e3) {
      if (i < e1) { if (i < e0) { s = s0; d = d0; j = i; } else { s = s1; d = d1; j = i - e0; } }
      else        { if (i < e2) { s = s2; d = d2; j = i - e1; } else { s = s3; d = d3; j = i - e2; } }
    } else {
      if (i < e5) { if (i < e4) { s = s4; d = d4; j = i - e3; } else { s = s5; d = d5; j = i - e4; } }
      else        { if (i < e6) { s = s6; d = d6; j = i - e5; } else { s = s7; d = d7; j = i - e6; } }
    }
    float4 v = ((const float4*)s)[j];
    us4 o;
    o[0] = f2bf(v.x); o[1] = f2bf(v.y); o[2] = f2bf(v.z); o[3] = f2bf(v.w);
    ((us4*)d)[j] = o;
  }
}

__global__ __launch_bounds__(256) void initct_k(const float* __restrict__ hidden,
                                                float* __restrict__ ctf,
                                                unsigned short* __restrict__ ctb) {
  int i = blockIdx.x * 256 + threadIdx.x;
  const int stride = gridDim.x * 256;
  for (; i < 524288; i += stride) {
    float4 v = ((const float4*)hidden)[524288 + i];
    ((float4*)ctf)[i] = v;
    us4 o;
    o[0] = f2bf(v.x); o[1] = f2bf(v.y); o[2] = f2bf(v.z); o[3] = f2bf(v.w);
    ((us4*)ctb)[i] = o;
  }
}

// ---------------------------------------------------------------------------
extern "C" void kernel_launch(void* const* d_in, const int* in_sizes, int n_in,
                              void* d_out, int out_size, void* d_ws, size_t ws_size,
                              hipStream_t stream) {
  (void)in_sizes; (void)n_in; (void)out_size; (void)ws_size;
  const float* hidden = (const float*)d_in[0];
  const float* q_w  = (const float*)d_in[1];
  const float* k_w  = (const float*)d_in[2];
  const float* v_w  = (const float*)d_in[3];
  const float* o_w  = (const float*)d_in[4];
  const float* a_nw = (const float*)d_in[5];
  const float* m_nw = (const float*)d_in[6];
  const float* g_w  = (const float*)d_in[7];
  const float* u_w  = (const float*)d_in[8];
  const float* dn_w = (const float*)d_in[9];
  float* out = (float*)d_out;

  char* p = (char*)d_ws;
  size_t off = 0;
  auto take = [&](size_t bytes) -> char* {
    char* r = p + off;
    off += (bytes + 255) & ~(size_t)255;
    return r;
  };
  float* ctf          = (float*)take((size_t)1024 * 2048 * 4);
  unsigned short* ctb = (unsigned short*)take((size_t)1024 * 2048 * 2);
  unsigned short* xb  = (unsigned short*)take((size_t)1024 * 2048 * 2);
  unsigned short* hb  = (unsigned short*)take((size_t)2048 * 2048 * 2);
  unsigned short* qwB = (unsigned short*)take((size_t)2048 * 2048 * 2);
  unsigned short* kwB = (unsigned short*)take((size_t)512 * 2048 * 2);
  unsigned short* vwB = (unsigned short*)take((size_t)512 * 2048 * 2);
  unsigned short* owB = (unsigned short*)take((size_t)2048 * 2048 * 2);
  unsigned short* gwB = (unsigned short*)take((size_t)5632 * 2048 * 2);
  unsigned short* uwB = (unsigned short*)take((size_t)5632 * 2048 * 2);
  unsigned short* dwB = (unsigned short*)take((size_t)2048 * 5632 * 2);
  unsigned short* qB  = (unsigned short*)take((size_t)1024 * 2048 * 2);
  unsigned short* kB  = (unsigned short*)take((size_t)3072 * 512 * 2);
  unsigned short* vtB = (unsigned short*)take((size_t)512 * 3072 * 2);
  unsigned short* oB  = (unsigned short*)take((size_t)1024 * 2048 * 2);
  unsigned short* gtB = (unsigned short*)take((size_t)1024 * 5632 * 2);

  // Attention split-KV scratch aliased over xb..hb (both dead during attn):
  // Op = 2*1024*2048 bf16 (8MB), Ml = 512KB right after.
  unsigned short* Op = xb;
  float* Ml = (float*)((char*)xb + (size_t)2 * 1024 * 2048 * 2);

  dim3 blk(256);
  cvt8_k<<<dim3(2048), blk, 0, stream>>>(hidden, q_w, k_w, v_w, o_w, g_w, u_w, dn_w,
                                         hb, qwB, kwB, vwB, owB, gwB, uwB, dwB);
  initct_k<<<dim3(1024), blk, 0, stream>>>(hidden, ctf, ctb);

  // K/V of the fixed hidden prefix (rows 0..2047): identical both layers
  gemm_dual<0><<<dim3(8, 32), blk, 0, stream>>>(hb, kwB, vwB, 2048, kB, vtB, 512, 3072);

  for (int it = 0; it < 2; it++) {
    rmsnorm_k<<<dim3(1024), blk, 0, stream>>>(ctf, a_nw, xb);
    gemm_bt<6><<<dim3(16, 16), blk, 0, stream>>>(xb, qwB, 2048, qB, nullptr, nullptr, 2048);
    gemm_dual<0><<<dim3(8, 16), blk, 0, stream>>>(ctb, kwB, vwB, 2048,
                                                  kB + (size_t)2048 * 512, vtB + 2048, 512, 3072);
    attn_k<<<dim3(16, 32, 2), blk, 0, stream>>>(qB, kB, vtB, Op, Ml);
    attn_combine<<<dim3(2048), blk, 0, stream>>>(Op, Ml, oB);
    gemm_bt<4><<<dim3(16, 16), blk, 0, stream>>>(oB, owB, 2048, nullptr, ctf, nullptr, 2048);
    rmsnorm_k<<<dim3(1024), blk, 0, stream>>>(ctf, m_nw, xb);
    gemm_dual<1><<<dim3(88, 16), blk, 0, stream>>>(xb, gwB, uwB, 2048, gtB, nullptr, 5632, 0);
    gemm_bt<5><<<dim3(16, 16), blk, 0, stream>>>(gtB, dwB, 5632, ctb,
                                                 (it == 1 ? out : ctf), xb, 2048);
  }
}

// Round 5
// 676.682 us; speedup vs baseline: 1.8077x; 1.0275x over previous
//
#include <hip/hip_runtime.h>

typedef __attribute__((ext_vector_type(8))) short short8;
typedef __attribute__((ext_vector_type(4))) float f32x4;
typedef __attribute__((ext_vector_type(4))) unsigned short us4;

__device__ __forceinline__ unsigned short f2bf(float f) {
  union { float f; unsigned u; } v; v.f = f;
  unsigned r = v.u + 0x7fffu + ((v.u >> 16) & 1u);
  return (unsigned short)(r >> 16);
}
__device__ __forceinline__ float bf2f(unsigned short b) {
  union { unsigned u; float f; } v; v.u = ((unsigned)b) << 16;
  return v.f;
}
__device__ __forceinline__ float fexp2(float x) {
  float r; asm("v_exp_f32 %0, %1" : "=v"(r) : "v"(x)); return r;
}

__device__ __forceinline__ void gload_lds16(const void* g, void* l) {
  __builtin_amdgcn_global_load_lds((const __attribute__((address_space(1))) void*)g,
                                   (__attribute__((address_space(3))) void*)l,
                                   16, 0, 0);
}

#define VMW6() asm volatile("s_waitcnt vmcnt(6)" ::: "memory")
#define VMW0() asm volatile("s_waitcnt vmcnt(0)" ::: "memory")
#define LGKM0() asm volatile("s_waitcnt lgkmcnt(0)" ::: "memory")

// ---- 128B-row (BK=64) staging/frag: LDS(row,g16) = global(row, g16^(row&7))
template<int R>
__device__ __forceinline__ void stage64(const unsigned short* g, int K, int k0,
                                        unsigned short* lds, int tid) {
  const int lane = tid & 63, w = tid >> 6;
  constexpr int RW = R / 4;
  constexpr int NL = RW / 8;
#pragma unroll
  for (int i = 0; i < NL; i++) {
    const int r0 = w * RW + i * 8;
    const int row = r0 + (lane >> 3);
    const int colb = (((lane & 7) ^ (lane >> 3)) << 4);
    gload_lds16((const char*)(g + (size_t)row * K + k0) + colb, lds + r0 * 64);
  }
}
__device__ __forceinline__ short8 lds_frag(const unsigned short* t, int row, int cb) {
  return *(const short8*)((const char*)t + row * 128 + (cb ^ ((row & 7) << 4)));
}

// ---- 64B-row (BK=32) staging/frag: LDS(row,g) = global(row, g^(row&3)), g in 16B
template<int R>
__device__ __forceinline__ void stage32(const unsigned short* g, int K, int k0,
                                        unsigned short* lds, int tid) {
  const int lane = tid & 63, w = tid >> 6;
  constexpr int RW = R / 4;    // rows per wave
  constexpr int NL = RW / 16;  // loads per thread (16 rows per load)
#pragma unroll
  for (int i = 0; i < NL; i++) {
    const int r0 = w * RW + i * 16;
    const int row = r0 + (lane >> 2);
    const int colb = (((lane & 3) ^ (lane >> 2)) & 3) << 4;
    gload_lds16((const char*)(g + (size_t)row * K + k0) + colb, lds + r0 * 32);
  }
}
__device__ __forceinline__ short8 frag32(const unsigned short* t, int row, int qo) {
  return *(const short8*)((const char*)t + row * 64 + (((qo ^ row) & 3) << 4));
}

// ---------------------------------------------------------------------------
// Single-B GEMM: C[M,N] = A[M,K] @ B[N,K]^T. BM=64, BN=128, BK=64, 3-buffer
// depth-2, counted vmcnt. EPI: 0 plain bf16; 4 outf[idx]+=v;
// 5 t=v+aux -> outf=t, outb=bf16(t); 6 bf16(v*qscale)
// ---------------------------------------------------------------------------
template<int EPI>
__global__ __launch_bounds__(256) void gemm_bt(
    const unsigned short* __restrict__ A,
    const unsigned short* __restrict__ B,
    int K,
    unsigned short* __restrict__ outb,
    float* __restrict__ outf,
    const unsigned short* __restrict__ aux,
    int ldo)
{
  constexpr int BM = 64, BN = 128, BK = 64;
  __shared__ __align__(16) unsigned short sA[3][BM * BK];
  __shared__ __align__(16) unsigned short sB[3][BN * BK];
  const int tid = threadIdx.x;
  const int lane = tid & 63, w = tid >> 6;
  const int wr = w >> 1, wc = w & 1;
  const int ln = lane & 15, qo = lane >> 4;
  const size_t m0 = (size_t)blockIdx.y * BM, n0 = (size_t)blockIdx.x * BN;
  const unsigned short* Ab = A + m0 * K;
  const unsigned short* Bb = B + n0 * K;

  const f32x4 z4 = {0.f, 0.f, 0.f, 0.f};
  f32x4 acc[2][4];
#pragma unroll
  for (int i = 0; i < 2; i++)
#pragma unroll
    for (int j = 0; j < 4; j++) acc[i][j] = z4;

  const int nt = K / BK;
  stage64<BM>(Ab, K, 0, sA[0], tid);
  stage64<BN>(Bb, K, 0, sB[0], tid);
  stage64<BM>(Ab, K, BK, sA[1], tid);
  stage64<BN>(Bb, K, BK, sB[1], tid);

  int cur = 0;
  for (int t = 0; t < nt; ++t) {
    if (t == nt - 1) VMW0(); else VMW6();
    __builtin_amdgcn_s_barrier();
    asm volatile("" ::: "memory");
    if (t + 2 < nt) {
      const int nx = (cur == 0) ? 2 : cur - 1;
      stage64<BM>(Ab, K, (t + 2) * BK, sA[nx], tid);
      stage64<BN>(Bb, K, (t + 2) * BK, sB[nx], tid);
    }
    const unsigned short* cA = sA[cur];
    const unsigned short* cB = sB[cur];
#pragma unroll
    for (int ks = 0; ks < 2; ks++) {
      short8 af[2], bfv[4];
#pragma unroll
      for (int mi = 0; mi < 2; mi++)
        af[mi] = lds_frag(cA, wr * 32 + mi * 16 + ln, ks * 64 + qo * 16);
#pragma unroll
      for (int ni = 0; ni < 4; ni++)
        bfv[ni] = lds_frag(cB, wc * 64 + ni * 16 + ln, ks * 64 + qo * 16);
      __builtin_amdgcn_s_setprio(1);
#pragma unroll
      for (int mi = 0; mi < 2; mi++)
#pragma unroll
        for (int ni = 0; ni < 4; ni++)
          acc[mi][ni] = __builtin_amdgcn_mfma_f32_16x16x32_bf16(af[mi], bfv[ni], acc[mi][ni], 0, 0, 0);
      __builtin_amdgcn_s_setprio(0);
    }
    cur = (cur == 2) ? 0 : cur + 1;
  }

#pragma unroll
  for (int mi = 0; mi < 2; mi++) {
#pragma unroll
    for (int ni = 0; ni < 4; ni++) {
      const size_t row4 = m0 + wr * 32 + mi * 16 + qo * 4;
      const size_t col  = n0 + wc * 64 + ni * 16 + ln;
#pragma unroll
      for (int r = 0; r < 4; r++) {
        const size_t idx = (row4 + r) * (size_t)ldo + col;
        float v = acc[mi][ni][r];
        if (EPI == 0) outb[idx] = f2bf(v);
        if (EPI == 4) outf[idx] += v;
        if (EPI == 5) { float t = v + bf2f(aux[idx]); outf[idx] = t; outb[idx] = f2bf(t); }
        if (EPI == 6) outb[idx] = f2bf(v * 0.18033688011112042f);  // 2^-3 * log2(e)
      }
    }
  }
}

// ---------------------------------------------------------------------------
// Big-tile GEMM for gate/up: BM=128, BN=256, BK=32, wave tile 64x128 (4 waves),
// 3-buffer depth-2, counted vmcnt. B is the 16-row-interleaved gate/up matrix
// guB[11264][2048]: combined row 32b+r = gate[16b+r] (r<16) / up[16b+r-16].
// Epilogue: out[row][16*(c>>5)+ln] = silu(g)*u with g=acc[.][2nj], u=acc[.][2nj+1].
// ---------------------------------------------------------------------------
__global__ __launch_bounds__(256, 2) void gemm_big(
    const unsigned short* __restrict__ A,
    const unsigned short* __restrict__ B,
    int K,
    unsigned short* __restrict__ outb,
    int ldo)
{
  constexpr int BM = 128, BN = 256, BK = 32;
  __shared__ __align__(16) unsigned short sA[3][BM * BK];
  __shared__ __align__(16) unsigned short sB[3][BN * BK];
  const int tid = threadIdx.x;
  const int lane = tid & 63, w = tid >> 6;
  const int wr = w >> 1, wc = w & 1;
  const int ln = lane & 15, qo = lane >> 4;
  const size_t m0 = (size_t)blockIdx.y * BM, n0 = (size_t)blockIdx.x * BN;
  const unsigned short* Ab = A + m0 * K;
  const unsigned short* Bb = B + n0 * K;

  const f32x4 z4 = {0.f, 0.f, 0.f, 0.f};
  f32x4 acc[4][8];
#pragma unroll
  for (int i = 0; i < 4; i++)
#pragma unroll
    for (int j = 0; j < 8; j++) acc[i][j] = z4;

  const int nt = K / BK;
  stage32<BM>(Ab, K, 0, sA[0], tid);
  stage32<BN>(Bb, K, 0, sB[0], tid);
  stage32<BM>(Ab, K, BK, sA[1], tid);
  stage32<BN>(Bb, K, BK, sB[1], tid);

  int cur = 0;
  for (int t = 0; t < nt; ++t) {
    if (t == nt - 1) VMW0(); else VMW6();
    __builtin_amdgcn_s_barrier();
    asm volatile("" ::: "memory");
    if (t + 2 < nt) {
      const int nx = (cur == 0) ? 2 : cur - 1;
      stage32<BM>(Ab, K, (t + 2) * BK, sA[nx], tid);
      stage32<BN>(Bb, K, (t + 2) * BK, sB[nx], tid);
    }
    const unsigned short* cA = sA[cur];
    const unsigned short* cB = sB[cur];
    short8 af[4], bfv[8];
#pragma unroll
    for (int mi = 0; mi < 4; mi++)
      af[mi] = frag32(cA, wr * 64 + mi * 16 + ln, qo);
#pragma unroll
    for (int ni = 0; ni < 8; ni++)
      bfv[ni] = frag32(cB, wc * 128 + ni * 16 + ln, qo);
    __builtin_amdgcn_s_setprio(1);
#pragma unroll
    for (int mi = 0; mi < 4; mi++)
#pragma unroll
      for (int ni = 0; ni < 8; ni++)
        acc[mi][ni] = __builtin_amdgcn_mfma_f32_16x16x32_bf16(af[mi], bfv[ni], acc[mi][ni], 0, 0, 0);
    __builtin_amdgcn_s_setprio(0);
    cur = (cur == 2) ? 0 : cur + 1;
  }

#pragma unroll
  for (int mi = 0; mi < 4; mi++) {
#pragma unroll
    for (int nj = 0; nj < 4; nj++) {
      const size_t row4 = m0 + wr * 64 + mi * 16 + qo * 4;
      const int c = (int)n0 + wc * 128 + nj * 32 + ln;   // combined (even) col
      const size_t cg = ((c >> 5) << 4) + ln;            // output col
#pragma unroll
      for (int r = 0; r < 4; r++) {
        float g = acc[mi][2 * nj][r], u = acc[mi][2 * nj + 1][r];
        outb[(row4 + r) * (size_t)ldo + cg] = f2bf(g / (1.f + __expf(-g)) * u);
      }
    }
  }
}

// ---------------------------------------------------------------------------
// Dual-B GEMM (K/V): shares A. BM=64, BN=64, BK=64. out0 bf16 row-major;
// out1 bf16 transposed.
// ---------------------------------------------------------------------------
__global__ __launch_bounds__(256) void gemm_dual(
    const unsigned short* __restrict__ A,
    const unsigned short* __restrict__ B0,
    const unsigned short* __restrict__ B1,
    int K,
    unsigned short* __restrict__ out0,
    unsigned short* __restrict__ out1,
    int ld0, int ld1)
{
  constexpr int BM = 64, BN = 64, BK = 64;
  __shared__ __align__(16) unsigned short sA[3][BM * BK];
  __shared__ __align__(16) unsigned short sB0[3][BN * BK];
  __shared__ __align__(16) unsigned short sB1[3][BN * BK];
  const int tid = threadIdx.x;
  const int lane = tid & 63, w = tid >> 6;
  const int wr = w >> 1, wc = w & 1;
  const int ln = lane & 15, qo = lane >> 4;
  const size_t m0 = (size_t)blockIdx.y * BM, n0 = (size_t)blockIdx.x * BN;
  const unsigned short* Ab = A + m0 * K;
  const unsigned short* B0b = B0 + n0 * K;
  const unsigned short* B1b = B1 + n0 * K;

  const f32x4 z4 = {0.f, 0.f, 0.f, 0.f};
  f32x4 acc0[2][2], acc1[2][2];
#pragma unroll
  for (int i = 0; i < 2; i++)
#pragma unroll
    for (int j = 0; j < 2; j++) { acc0[i][j] = z4; acc1[i][j] = z4; }

  const int nt = K / BK;
  stage64<BM>(Ab, K, 0, sA[0], tid);
  stage64<BN>(B0b, K, 0, sB0[0], tid);
  stage64<BN>(B1b, K, 0, sB1[0], tid);
  stage64<BM>(Ab, K, BK, sA[1], tid);
  stage64<BN>(B0b, K, BK, sB0[1], tid);
  stage64<BN>(B1b, K, BK, sB1[1], tid);

  int cur = 0;
  for (int t = 0; t < nt; ++t) {
    if (t == nt - 1) VMW0(); else VMW6();
    __builtin_amdgcn_s_barrier();
    asm volatile("" ::: "memory");
    if (t + 2 < nt) {
      const int nx = (cur == 0) ? 2 : cur - 1;
      stage64<BM>(Ab, K, (t + 2) * BK, sA[nx], tid);
      stage64<BN>(B0b, K, (t + 2) * BK, sB0[nx], tid);
      stage64<BN>(B1b, K, (t + 2) * BK, sB1[nx], tid);
    }
    const unsigned short* cA = sA[cur];
    const unsigned short* cB0 = sB0[cur];
    const unsigned short* cB1 = sB1[cur];
#pragma unroll
    for (int ks = 0; ks < 2; ks++) {
      short8 af[2], b0f[2], b1f[2];
#pragma unroll
      for (int mi = 0; mi < 2; mi++)
        af[mi] = lds_frag(cA, wr * 32 + mi * 16 + ln, ks * 64 + qo * 16);
#pragma unroll
      for (int ni = 0; ni < 2; ni++) {
        b0f[ni] = lds_frag(cB0, wc * 32 + ni * 16 + ln, ks * 64 + qo * 16);
        b1f[ni] = lds_frag(cB1, wc * 32 + ni * 16 + ln, ks * 64 + qo * 16);
      }
      __builtin_amdgcn_s_setprio(1);
#pragma unroll
      for (int mi = 0; mi < 2; mi++)
#pragma unroll
        for (int ni = 0; ni < 2; ni++) {
          acc0[mi][ni] = __builtin_amdgcn_mfma_f32_16x16x32_bf16(af[mi], b0f[ni], acc0[mi][ni], 0, 0, 0);
          acc1[mi][ni] = __builtin_amdgcn_mfma_f32_16x16x32_bf16(af[mi], b1f[ni], acc1[mi][ni], 0, 0, 0);
        }
      __builtin_amdgcn_s_setprio(0);
    }
    cur = (cur == 2) ? 0 : cur + 1;
  }

#pragma unroll
  for (int mi = 0; mi < 2; mi++) {
#pragma unroll
    for (int ni = 0; ni < 2; ni++) {
      const size_t row4 = m0 + wr * 32 + mi * 16 + qo * 4;
      const size_t col  = n0 + wc * 32 + ni * 16 + ln;
#pragma unroll
      for (int r = 0; r < 4; r++)
        out0[(row4 + r) * (size_t)ld0 + col] = f2bf(acc0[mi][ni][r]);
      us4 pk;
      pk[0] = f2bf(acc1[mi][ni][0]); pk[1] = f2bf(acc1[mi][ni][1]);
      pk[2] = f2bf(acc1[mi][ni][2]); pk[3] = f2bf(acc1[mi][ni][3]);
      *(us4*)&out1[col * (size_t)ld1 + row4] = pk;
    }
  }
}

// ---------------------------------------------------------------------------
// Flash attention, split-KV by 2 (as in R4).
// ---------------------------------------------------------------------------
__global__ __launch_bounds__(256) void attn_k(
    const unsigned short* __restrict__ Q,
    const unsigned short* __restrict__ Kb,
    const unsigned short* __restrict__ Vt,
    unsigned short* __restrict__ Op,
    float* __restrict__ Ml)
{
  __shared__ __align__(16) unsigned short sK[2][64 * 64];
  __shared__ __align__(16) unsigned short sV[2][64 * 64];
  __shared__ __align__(16) unsigned short sP[64 * 64];
  const int tid = threadIdx.x;
  const int lane = tid & 63, w = tid >> 6;
  const int ln = lane & 15, qo = lane >> 4;
  const int head = blockIdx.y, kvh = head >> 2;
  const int half = blockIdx.z;
  const int qw = blockIdx.x * 64 + w * 16;
  const int key0 = half * 1536;

  short8 qf[2];
  qf[0] = *(const short8*)&Q[(size_t)(qw + ln) * 2048 + head * 64 + qo * 8];
  qf[1] = *(const short8*)&Q[(size_t)(qw + ln) * 2048 + head * 64 + 32 + qo * 8];

  const f32x4 z4 = {0.f, 0.f, 0.f, 0.f};
  f32x4 oacc[4] = {z4, z4, z4, z4};
  float mrun = -1e30f, lrun = 0.f;

  const unsigned short* Kg = Kb + kvh * 64;
  const unsigned short* Vg = Vt + (size_t)(kvh * 64) * 3072;

  stage64<64>(Kg + (size_t)key0 * 512, 512, 0, sK[0], tid);
  stage64<64>(Vg, 3072, key0, sV[0], tid);

  for (int t = 0; t < 24; ++t) {
    const int cur = t & 1;
    VMW0();
    __builtin_amdgcn_s_barrier();
    asm volatile("" ::: "memory");
    if (t + 1 < 24) {
      stage64<64>(Kg + (size_t)(key0 + (t + 1) * 64) * 512, 512, 0, sK[cur ^ 1], tid);
      stage64<64>(Vg, 3072, key0 + (t + 1) * 64, sV[cur ^ 1], tid);
    }

    f32x4 sacc[4] = {z4, z4, z4, z4};
#pragma unroll
    for (int kc = 0; kc < 2; kc++) {
      short8 kf[4];
#pragma unroll
      for (int mi = 0; mi < 4; mi++)
        kf[mi] = lds_frag(sK[cur], mi * 16 + ln, kc * 64 + qo * 16);
      __builtin_amdgcn_s_setprio(1);
#pragma unroll
      for (int mi = 0; mi < 4; mi++)
        sacc[mi] = __builtin_amdgcn_mfma_f32_16x16x32_bf16(kf[mi], qf[kc], sacc[mi], 0, 0, 0);
      __builtin_amdgcn_s_setprio(0);
    }

    float tm = -1e30f;
#pragma unroll
    for (int mi = 0; mi < 4; mi++) {
      float a0 = fmaxf(sacc[mi][0], sacc[mi][1]);
      float a1 = fmaxf(sacc[mi][2], sacc[mi][3]);
      tm = fmaxf(tm, fmaxf(a0, a1));
    }
    tm = fmaxf(tm, __shfl_xor(tm, 16));
    tm = fmaxf(tm, __shfl_xor(tm, 32));

    if (!__all(tm <= mrun + 11.f)) {
      const float mn = fmaxf(mrun, tm);
      const float al = fexp2(mrun - mn);
      lrun *= al;
      mrun = mn;
#pragma unroll
      for (int r = 0; r < 4; r++) {
        float ar = __shfl(al, qo * 4 + r);
#pragma unroll
        for (int ni = 0; ni < 4; ni++) oacc[ni][r] *= ar;
      }
    }

    float ts = 0.f;
#pragma unroll
    for (int mi = 0; mi < 4; mi++) {
      us4 pk;
#pragma unroll
      for (int r = 0; r < 4; r++) {
        float pv = fexp2(sacc[mi][r] - mrun);
        ts += pv;
        pk[r] = f2bf(pv);
      }
      const int row = w * 16 + ln;
      const int g16 = (2 * mi + (qo >> 1)) ^ (ln & 7);
      *(us4*)((char*)sP + row * 128 + (g16 << 4) + ((qo & 1) << 3)) = pk;
    }
    ts += __shfl_xor(ts, 16);
    ts += __shfl_xor(ts, 32);
    lrun += ts;

#pragma unroll
    for (int ks = 0; ks < 2; ks++) {
      short8 pf = lds_frag(sP, w * 16 + ln, ks * 64 + qo * 16);
      short8 vf[4];
#pragma unroll
      for (int ni = 0; ni < 4; ni++)
        vf[ni] = lds_frag(sV[cur], ni * 16 + ln, ks * 64 + qo * 16);
      __builtin_amdgcn_s_setprio(1);
#pragma unroll
      for (int ni = 0; ni < 4; ni++)
        oacc[ni] = __builtin_amdgcn_mfma_f32_16x16x32_bf16(pf, vf[ni], oacc[ni], 0, 0, 0);
      __builtin_amdgcn_s_setprio(0);
    }
    LGKM0();
  }

  if (qo == 0)
    *(float2*)&Ml[((size_t)(half * 32 + head) * 1024 + qw + ln) * 2] =
        make_float2(mrun, lrun);
#pragma unroll
  for (int r = 0; r < 4; r++)
#pragma unroll
    for (int ni = 0; ni < 4; ni++)
      Op[(size_t)half * 2097152 + (size_t)(qw + qo * 4 + r) * 2048 + head * 64 + ni * 16 + ln] =
          f2bf(oacc[ni][r]);
}

__global__ __launch_bounds__(256) void attn_combine(
    const unsigned short* __restrict__ Op,
    const float* __restrict__ Ml,
    unsigned short* __restrict__ O)
{
  const int f = blockIdx.x * 256 + threadIdx.x;
  const int q = f >> 9;
  const int c = (f & 511) * 4;
  const int head = c >> 6;
  const float2 ml0 = *(const float2*)&Ml[((size_t)head * 1024 + q) * 2];
  const float2 ml1 = *(const float2*)&Ml[((size_t)(32 + head) * 1024 + q) * 2];
  const float m = fmaxf(ml0.x, ml1.x);
  const float w0 = fexp2(ml0.x - m), w1 = fexp2(ml1.x - m);
  const float inv = 1.f / (w0 * ml0.y + w1 * ml1.y);
  const us4 o0 = *(const us4*)&Op[(size_t)q * 2048 + c];
  const us4 o1 = *(const us4*)&Op[2097152 + (size_t)q * 2048 + c];
  us4 o;
#pragma unroll
  for (int j = 0; j < 4; j++)
    o[j] = f2bf((w0 * bf2f(o0[j]) + w1 * bf2f(o1[j])) * inv);
  *(us4*)&O[(size_t)q * 2048 + c] = o;
}

// ---------------------------------------------------------------------------
__global__ __launch_bounds__(256) void rmsnorm_k(const float* __restrict__ in,
                                                 const float* __restrict__ w,
                                                 unsigned short* __restrict__ out) {
  const int row = blockIdx.x;
  const int tid = threadIdx.x;
  const float* x = in + (size_t)row * 2048;
  float4 a = ((const float4*)x)[tid * 2];
  float4 b = ((const float4*)x)[tid * 2 + 1];
  float ss = a.x * a.x + a.y * a.y + a.z * a.z + a.w * a.w +
             b.x * b.x + b.y * b.y + b.z * b.z + b.w * b.w;
#pragma unroll
  for (int d = 1; d < 64; d <<= 1) ss += __shfl_xor(ss, d);
  __shared__ float red[4];
  if ((tid & 63) == 0) red[tid >> 6] = ss;
  __syncthreads();
  float sc = rsqrtf((red[0] + red[1] + red[2] + red[3]) * (1.f / 2048.f) + 1e-6f);
  float4 wa = ((const float4*)w)[tid * 2];
  float4 wb = ((const float4*)w)[tid * 2 + 1];
  us4 o1, o2;
  o1[0] = f2bf(a.x * sc * wa.x); o1[1] = f2bf(a.y * sc * wa.y);
  o1[2] = f2bf(a.z * sc * wa.z); o1[3] = f2bf(a.w * sc * wa.w);
  o2[0] = f2bf(b.x * sc * wb.x); o2[1] = f2bf(b.y * sc * wb.y);
  o2[2] = f2bf(b.z * sc * wb.z); o2[3] = f2bf(b.w * sc * wb.w);
  us4* op = (us4*)&out[(size_t)row * 2048 + tid * 8];
  op[0] = o1; op[1] = o2;
}

// Converts all fp32 inputs to bf16. Segments 5 (gate) and 6 (up) are written
// 16-row-interleaved into the combined guB: gate row i -> 32*(i>>4)+(i&15),
// up row i -> 32*(i>>4)+16+(i&15). Rows are 2048 f32 = 512 float4.
__global__ __launch_bounds__(256) void cvt8_k(
    const float* __restrict__ s0, const float* __restrict__ s1,
    const float* __restrict__ s2, const float* __restrict__ s3,
    const float* __restrict__ s4, const float* __restrict__ s5,
    const float* __restrict__ s6, const float* __restrict__ s7,
    unsigned short* __restrict__ d0, unsigned short* __restrict__ d1,
    unsigned short* __restrict__ d2, unsigned short* __restrict__ d3,
    unsigned short* __restrict__ d4, unsigned short* __restrict__ dgu,
    unsigned short* __restrict__ d7)
{
  const int e0 = 1048576, e1 = 2097152, e2 = 2359296, e3 = 2621440,
            e4 = 3670016, e5 = 6553600, e6 = 9437184, e7 = 12320768;
  int i = blockIdx.x * 256 + threadIdx.x;
  const int stride = gridDim.x * 256;
  for (; i < e7; i += stride) {
    const float* s; unsigned short* d; int j; int gu = 0;
    if (i < e3) {
      if (i < e1) { if (i < e0) { s = s0; d = d0; j = i; } else { s = s1; d = d1; j = i - e0; } }
      else        { if (i < e2) { s = s2; d = d2; j = i - e1; } else { s = s3; d = d3; j = i - e2; } }
    } else {
      if (i < e5) { if (i < e4) { s = s4; d = d4; j = i - e3; } else { s = s5; d = dgu; j = i - e4; gu = 1; } }
      else        { if (i < e6) { s = s6; d = dgu; j = i - e5; gu = 2; } else { s = s7; d = d7; j = i - e6; } }
    }
    float4 v = ((const float4*)s)[j];
    us4 o;
    o[0] = f2bf(v.x); o[1] = f2bf(v.y); o[2] = f2bf(v.z); o[3] = f2bf(v.w);
    int jd = j;
    if (gu) {
      const int row = j >> 9, c4 = j & 511;
      const int drow = ((row >> 4) << 5) + (row & 15) + ((gu == 2) ? 16 : 0);
      jd = (drow << 9) + c4;
    }
    ((us4*)d)[jd] = o;
  }
}

__global__ __launch_bounds__(256) void initct_k(const float* __restrict__ hidden,
                                                float* __restrict__ ctf,
                                                unsigned short* __restrict__ ctb) {
  int i = blockIdx.x * 256 + threadIdx.x;
  const int stride = gridDim.x * 256;
  for (; i < 524288; i += stride) {
    float4 v = ((const float4*)hidden)[524288 + i];
    ((float4*)ctf)[i] = v;
    us4 o;
    o[0] = f2bf(v.x); o[1] = f2bf(v.y); o[2] = f2bf(v.z); o[3] = f2bf(v.w);
    ((us4*)ctb)[i] = o;
  }
}

// ---------------------------------------------------------------------------
extern "C" void kernel_launch(void* const* d_in, const int* in_sizes, int n_in,
                              void* d_out, int out_size, void* d_ws, size_t ws_size,
                              hipStream_t stream) {
  (void)in_sizes; (void)n_in; (void)out_size; (void)ws_size;
  const float* hidden = (const float*)d_in[0];
  const float* q_w  = (const float*)d_in[1];
  const float* k_w  = (const float*)d_in[2];
  const float* v_w  = (const float*)d_in[3];
  const float* o_w  = (const float*)d_in[4];
  const float* a_nw = (const float*)d_in[5];
  const float* m_nw = (const float*)d_in[6];
  const float* g_w  = (const float*)d_in[7];
  const float* u_w  = (const float*)d_in[8];
  const float* dn_w = (const float*)d_in[9];
  float* out = (float*)d_out;

  char* p = (char*)d_ws;
  size_t off = 0;
  auto take = [&](size_t bytes) -> char* {
    char* r = p + off;
    off += (bytes + 255) & ~(size_t)255;
    return r;
  };
  float* ctf          = (float*)take((size_t)1024 * 2048 * 4);
  unsigned short* ctb = (unsigned short*)take((size_t)1024 * 2048 * 2);
  unsigned short* xb  = (unsigned short*)take((size_t)1024 * 2048 * 2);
  unsigned short* hb  = (unsigned short*)take((size_t)2048 * 2048 * 2);
  unsigned short* qwB = (unsigned short*)take((size_t)2048 * 2048 * 2);
  unsigned short* kwB = (unsigned short*)take((size_t)512 * 2048 * 2);
  unsigned short* vwB = (unsigned short*)take((size_t)512 * 2048 * 2);
  unsigned short* owB = (unsigned short*)take((size_t)2048 * 2048 * 2);
  unsigned short* guB = (unsigned short*)take((size_t)11264 * 2048 * 2);
  unsigned short* dwB = (unsigned short*)take((size_t)2048 * 5632 * 2);
  unsigned short* qB  = (unsigned short*)take((size_t)1024 * 2048 * 2);
  unsigned short* kB  = (unsigned short*)take((size_t)3072 * 512 * 2);
  unsigned short* vtB = (unsigned short*)take((size_t)512 * 3072 * 2);
  unsigned short* oB  = (unsigned short*)take((size_t)1024 * 2048 * 2);
  unsigned short* gtB = (unsigned short*)take((size_t)1024 * 5632 * 2);

  unsigned short* Op = xb;  // attn scratch aliased over xb+hb (dead there)
  float* Ml = (float*)((char*)xb + (size_t)2 * 1024 * 2048 * 2);

  dim3 blk(256);
  cvt8_k<<<dim3(2048), blk, 0, stream>>>(hidden, q_w, k_w, v_w, o_w, g_w, u_w, dn_w,
                                         hb, qwB, kwB, vwB, owB, guB, dwB);
  initct_k<<<dim3(1024), blk, 0, stream>>>(hidden, ctf, ctb);

  gemm_dual<<<dim3(8, 32), blk, 0, stream>>>(hb, kwB, vwB, 2048, kB, vtB, 512, 3072);

  for (int it = 0; it < 2; it++) {
    rmsnorm_k<<<dim3(1024), blk, 0, stream>>>(ctf, a_nw, xb);
    gemm_bt<6><<<dim3(16, 16), blk, 0, stream>>>(xb, qwB, 2048, qB, nullptr, nullptr, 2048);
    gemm_dual<<<dim3(8, 16), blk, 0, stream>>>(ctb, kwB, vwB, 2048,
                                               kB + (size_t)2048 * 512, vtB + 2048, 512, 3072);
    attn_k<<<dim3(16, 32, 2), blk, 0, stream>>>(qB, kB, vtB, Op, Ml);
    attn_combine<<<dim3(2048), blk, 0, stream>>>(Op, Ml, oB);
    gemm_bt<4><<<dim3(16, 16), blk, 0, stream>>>(oB, owB, 2048, nullptr, ctf, nullptr, 2048);
    rmsnorm_k<<<dim3(1024), blk, 0, stream>>>(ctf, m_nw, xb);
    gemm_big<<<dim3(44, 8), blk, 0, stream>>>(xb, guB, 2048, gtB, 5632);
    gemm_bt<5><<<dim3(16, 16), blk, 0, stream>>>(gtB, dwB, 5632, ctb,
                                                 (it == 1 ? out : ctf), xb, 2048);
  }
}

// Round 7
// 569.515 us; speedup vs baseline: 2.1479x; 1.1882x over previous
//
#include <hip/hip_runtime.h>

typedef __attribute__((ext_vector_type(8))) short short8;
typedef __attribute__((ext_vector_type(4))) float f32x4;
typedef __attribute__((ext_vector_type(4))) unsigned short us4;

__device__ __forceinline__ unsigned short f2bf(float f) {
  union { float f; unsigned u; } v; v.f = f;
  unsigned r = v.u + 0x7fffu + ((v.u >> 16) & 1u);
  return (unsigned short)(r >> 16);
}
__device__ __forceinline__ float bf2f(unsigned short b) {
  union { unsigned u; float f; } v; v.u = ((unsigned)b) << 16;
  return v.f;
}
__device__ __forceinline__ float fexp2(float x) {
  float r; asm("v_exp_f32 %0, %1" : "=v"(r) : "v"(x)); return r;
}

__device__ __forceinline__ void gload_lds16(const void* g, void* l) {
  __builtin_amdgcn_global_load_lds((const __attribute__((address_space(1))) void*)g,
                                   (__attribute__((address_space(3))) void*)l,
                                   16, 0, 0);
}

#define VMW6() asm volatile("s_waitcnt vmcnt(6)" ::: "memory")
#define VMW0() asm volatile("s_waitcnt vmcnt(0)" ::: "memory")
#define LGKM0() asm volatile("s_waitcnt lgkmcnt(0)" ::: "memory")

// ---- 128B-row (BK=64) staging/frag: LDS(row,g16) = global(row, g16^(row&7))
template<int R>
__device__ __forceinline__ void stage64(const unsigned short* g, int K, int k0,
                                        unsigned short* lds, int tid) {
  const int lane = tid & 63, w = tid >> 6;
  constexpr int RW = R / 4;
  constexpr int NL = RW / 8;
#pragma unroll
  for (int i = 0; i < NL; i++) {
    const int r0 = w * RW + i * 8;
    const int row = r0 + (lane >> 3);
    const int colb = (((lane & 7) ^ (lane >> 3)) << 4);
    gload_lds16((const char*)(g + (size_t)row * K + k0) + colb, lds + r0 * 64);
  }
}
__device__ __forceinline__ short8 lds_frag(const unsigned short* t, int row, int cb) {
  return *(const short8*)((const char*)t + row * 128 + (cb ^ ((row & 7) << 4)));
}

// ---------------------------------------------------------------------------
// Split-K GEMM: P[z][M=1024][ldo] (fp32) = A[M,K(z-half)] @ B[N,K]^T.
// BM=64, BN=128, BK=64, 3-buffer depth-2, vmcnt(6). Grid (N/128, 16, 2).
// ---------------------------------------------------------------------------
__global__ __launch_bounds__(256) void gemm_split(
    const unsigned short* __restrict__ A,
    const unsigned short* __restrict__ B,
    int K,
    float* __restrict__ P,
    int ldo)
{
  constexpr int BM = 64, BN = 128, BK = 64;
  __shared__ __align__(16) unsigned short sA[3][BM * BK];
  __shared__ __align__(16) unsigned short sB[3][BN * BK];
  const int tid = threadIdx.x;
  const int lane = tid & 63, w = tid >> 6;
  const int wr = w >> 1, wc = w & 1;
  const int ln = lane & 15, qo = lane >> 4;
  const size_t m0 = (size_t)blockIdx.y * BM, n0 = (size_t)blockIdx.x * BN;
  const int koff = blockIdx.z * (K >> 1);
  const unsigned short* Ab = A + m0 * K;
  const unsigned short* Bb = B + n0 * K;

  const f32x4 z4 = {0.f, 0.f, 0.f, 0.f};
  f32x4 acc[2][4];
#pragma unroll
  for (int i = 0; i < 2; i++)
#pragma unroll
    for (int j = 0; j < 4; j++) acc[i][j] = z4;

  const int nt = K / (2 * BK);
  stage64<BM>(Ab, K, koff, sA[0], tid);
  stage64<BN>(Bb, K, koff, sB[0], tid);
  stage64<BM>(Ab, K, koff + BK, sA[1], tid);
  stage64<BN>(Bb, K, koff + BK, sB[1], tid);

  int cur = 0;
  for (int t = 0; t < nt; ++t) {
    if (t == nt - 1) VMW0(); else VMW6();
    __builtin_amdgcn_s_barrier();
    asm volatile("" ::: "memory");
    if (t + 2 < nt) {
      const int nx = (cur == 0) ? 2 : cur - 1;
      stage64<BM>(Ab, K, koff + (t + 2) * BK, sA[nx], tid);
      stage64<BN>(Bb, K, koff + (t + 2) * BK, sB[nx], tid);
    }
    const unsigned short* cA = sA[cur];
    const unsigned short* cB = sB[cur];
#pragma unroll
    for (int ks = 0; ks < 2; ks++) {
      short8 af[2], bfv[4];
#pragma unroll
      for (int mi = 0; mi < 2; mi++)
        af[mi] = lds_frag(cA, wr * 32 + mi * 16 + ln, ks * 64 + qo * 16);
#pragma unroll
      for (int ni = 0; ni < 4; ni++)
        bfv[ni] = lds_frag(cB, wc * 64 + ni * 16 + ln, ks * 64 + qo * 16);
      __builtin_amdgcn_s_setprio(1);
#pragma unroll
      for (int mi = 0; mi < 2; mi++)
#pragma unroll
        for (int ni = 0; ni < 4; ni++)
          acc[mi][ni] = __builtin_amdgcn_mfma_f32_16x16x32_bf16(af[mi], bfv[ni], acc[mi][ni], 0, 0, 0);
      __builtin_amdgcn_s_setprio(0);
    }
    cur = (cur == 2) ? 0 : cur + 1;
  }

  float* Pz = P + (size_t)blockIdx.z * 1024 * (size_t)ldo;
#pragma unroll
  for (int mi = 0; mi < 2; mi++) {
#pragma unroll
    for (int ni = 0; ni < 4; ni++) {
      const size_t row4 = m0 + wr * 32 + mi * 16 + qo * 4;
      const size_t col  = n0 + wc * 64 + ni * 16 + ln;
#pragma unroll
      for (int r = 0; r < 4; r++)
        Pz[(row4 + r) * (size_t)ldo + col] = acc[mi][ni][r];
    }
  }
}

// ---------------------------------------------------------------------------
// Gate/Up GEMM: BM=128, BN=128 (combined interleaved cols), BK=64, 2-buffer
// double-buffer (64KB LDS -> 2 blocks/CU). Wave tile 64x64.
// B = guB[11264][2048], 16-row interleave; epilogue silu(g)*u.
// ---------------------------------------------------------------------------
__global__ __launch_bounds__(256) void gemm_gu(
    const unsigned short* __restrict__ A,
    const unsigned short* __restrict__ B,
    unsigned short* __restrict__ outb)
{
  __shared__ __align__(16) unsigned short sA[2][128 * 64];
  __shared__ __align__(16) unsigned short sB[2][128 * 64];
  const int tid = threadIdx.x;
  const int lane = tid & 63, w = tid >> 6;
  const int wr = w >> 1, wc = w & 1;
  const int ln = lane & 15, qo = lane >> 4;
  const size_t m0 = (size_t)blockIdx.y * 128, n0 = (size_t)blockIdx.x * 128;
  const unsigned short* Ab = A + m0 * 2048;
  const unsigned short* Bb = B + n0 * 2048;

  const f32x4 z4 = {0.f, 0.f, 0.f, 0.f};
  f32x4 acc[4][4];
#pragma unroll
  for (int i = 0; i < 4; i++)
#pragma unroll
    for (int j = 0; j < 4; j++) acc[i][j] = z4;

  stage64<128>(Ab, 2048, 0, sA[0], tid);
  stage64<128>(Bb, 2048, 0, sB[0], tid);

  for (int t = 0; t < 32; ++t) {
    const int cur = t & 1;
    VMW0();
    __builtin_amdgcn_s_barrier();
    asm volatile("" ::: "memory");
    if (t + 1 < 32) {
      stage64<128>(Ab, 2048, (t + 1) * 64, sA[cur ^ 1], tid);
      stage64<128>(Bb, 2048, (t + 1) * 64, sB[cur ^ 1], tid);
    }
    const unsigned short* cA = sA[cur];
    const unsigned short* cB = sB[cur];
#pragma unroll
    for (int ks = 0; ks < 2; ks++) {
      short8 af[4], bfv[4];
#pragma unroll
      for (int mi = 0; mi < 4; mi++)
        af[mi] = lds_frag(cA, wr * 64 + mi * 16 + ln, ks * 64 + qo * 16);
#pragma unroll
      for (int ni = 0; ni < 4; ni++)
        bfv[ni] = lds_frag(cB, wc * 64 + ni * 16 + ln, ks * 64 + qo * 16);
      __builtin_amdgcn_s_setprio(1);
#pragma unroll
      for (int mi = 0; mi < 4; mi++)
#pragma unroll
        for (int ni = 0; ni < 4; ni++)
          acc[mi][ni] = __builtin_amdgcn_mfma_f32_16x16x32_bf16(af[mi], bfv[ni], acc[mi][ni], 0, 0, 0);
      __builtin_amdgcn_s_setprio(0);
    }
  }

  // pairs: gate = acc[mi][2j], up = acc[mi][2j+1]; out col = n0/2 + wc*32 + j*16 + ln
#pragma unroll
  for (int mi = 0; mi < 4; mi++) {
#pragma unroll
    for (int j = 0; j < 2; j++) {
      const size_t row4 = m0 + wr * 64 + mi * 16 + qo * 4;
      const size_t cg = (n0 >> 1) + wc * 32 + j * 16 + ln;
#pragma unroll
      for (int r = 0; r < 4; r++) {
        float g = acc[mi][2 * j][r], u = acc[mi][2 * j + 1][r];
        outb[(row4 + r) * 5632 + cg] = f2bf(g / (1.f + __expf(-g)) * u);
      }
    }
  }
}

// ---------------------------------------------------------------------------
// Dual-B GEMM (K/V): shares A. BM=64, BN=64, BK=64.
// SPLIT=0: out0 bf16 row-major (ld0), out1 bf16 transposed (ld1).
// SPLIT=1: fp32 partials P[z][1024][1024] (K cols 0-511, V cols 512-1023).
// ---------------------------------------------------------------------------
template<int SPLIT>
__global__ __launch_bounds__(256) void gemm_dual(
    const unsigned short* __restrict__ A,
    const unsigned short* __restrict__ B0,
    const unsigned short* __restrict__ B1,
    int K,
    unsigned short* __restrict__ out0,
    unsigned short* __restrict__ out1,
    float* __restrict__ P,
    int ld0, int ld1)
{
  constexpr int BM = 64, BN = 64, BK = 64;
  __shared__ __align__(16) unsigned short sA[3][BM * BK];
  __shared__ __align__(16) unsigned short sB0[3][BN * BK];
  __shared__ __align__(16) unsigned short sB1[3][BN * BK];
  const int tid = threadIdx.x;
  const int lane = tid & 63, w = tid >> 6;
  const int wr = w >> 1, wc = w & 1;
  const int ln = lane & 15, qo = lane >> 4;
  const size_t m0 = (size_t)blockIdx.y * BM, n0 = (size_t)blockIdx.x * BN;
  const int koff = SPLIT ? blockIdx.z * (K >> 1) : 0;
  const unsigned short* Ab = A + m0 * K;
  const unsigned short* B0b = B0 + n0 * K;
  const unsigned short* B1b = B1 + n0 * K;

  const f32x4 z4 = {0.f, 0.f, 0.f, 0.f};
  f32x4 acc0[2][2], acc1[2][2];
#pragma unroll
  for (int i = 0; i < 2; i++)
#pragma unroll
    for (int j = 0; j < 2; j++) { acc0[i][j] = z4; acc1[i][j] = z4; }

  const int nt = SPLIT ? K / (2 * BK) : K / BK;
  stage64<BM>(Ab, K, koff, sA[0], tid);
  stage64<BN>(B0b, K, koff, sB0[0], tid);
  stage64<BN>(B1b, K, koff, sB1[0], tid);
  stage64<BM>(Ab, K, koff + BK, sA[1], tid);
  stage64<BN>(B0b, K, koff + BK, sB0[1], tid);
  stage64<BN>(B1b, K, koff + BK, sB1[1], tid);

  int cur = 0;
  for (int t = 0; t < nt; ++t) {
    if (t == nt - 1) VMW0(); else VMW6();
    __builtin_amdgcn_s_barrier();
    asm volatile("" ::: "memory");
    if (t + 2 < nt) {
      const int nx = (cur == 0) ? 2 : cur - 1;
      stage64<BM>(Ab, K, koff + (t + 2) * BK, sA[nx], tid);
      stage64<BN>(B0b, K, koff + (t + 2) * BK, sB0[nx], tid);
      stage64<BN>(B1b, K, koff + (t + 2) * BK, sB1[nx], tid);
    }
    const unsigned short* cA = sA[cur];
    const unsigned short* cB0 = sB0[cur];
    const unsigned short* cB1 = sB1[cur];
#pragma unroll
    for (int ks = 0; ks < 2; ks++) {
      short8 af[2], b0f[2], b1f[2];
#pragma unroll
      for (int mi = 0; mi < 2; mi++)
        af[mi] = lds_frag(cA, wr * 32 + mi * 16 + ln, ks * 64 + qo * 16);
#pragma unroll
      for (int ni = 0; ni < 2; ni++) {
        b0f[ni] = lds_frag(cB0, wc * 32 + ni * 16 + ln, ks * 64 + qo * 16);
        b1f[ni] = lds_frag(cB1, wc * 32 + ni * 16 + ln, ks * 64 + qo * 16);
      }
      __builtin_amdgcn_s_setprio(1);
#pragma unroll
      for (int mi = 0; mi < 2; mi++)
#pragma unroll
        for (int ni = 0; ni < 2; ni++) {
          acc0[mi][ni] = __builtin_amdgcn_mfma_f32_16x16x32_bf16(af[mi], b0f[ni], acc0[mi][ni], 0, 0, 0);
          acc1[mi][ni] = __builtin_amdgcn_mfma_f32_16x16x32_bf16(af[mi], b1f[ni], acc1[mi][ni], 0, 0, 0);
        }
      __builtin_amdgcn_s_setprio(0);
    }
    cur = (cur == 2) ? 0 : cur + 1;
  }

#pragma unroll
  for (int mi = 0; mi < 2; mi++) {
#pragma unroll
    for (int ni = 0; ni < 2; ni++) {
      const size_t row4 = m0 + wr * 32 + mi * 16 + qo * 4;
      const size_t col  = n0 + wc * 32 + ni * 16 + ln;
      if (SPLIT) {
        float* Pz = P + (size_t)blockIdx.z * 1048576;
#pragma unroll
        for (int r = 0; r < 4; r++) {
          Pz[(row4 + r) * 1024 + col] = acc0[mi][ni][r];
          Pz[(row4 + r) * 1024 + 512 + col] = acc1[mi][ni][r];
        }
      } else {
#pragma unroll
        for (int r = 0; r < 4; r++)
          out0[(row4 + r) * (size_t)ld0 + col] = f2bf(acc0[mi][ni][r]);
        us4 pk;
        pk[0] = f2bf(acc1[mi][ni][0]); pk[1] = f2bf(acc1[mi][ni][1]);
        pk[2] = f2bf(acc1[mi][ni][2]); pk[3] = f2bf(acc1[mi][ni][3]);
        *(us4*)&out1[col * (size_t)ld1 + row4] = pk;
      }
    }
  }
}

// Combine split-KV partials: kB rows (coalesced) + vtB transposed.
__global__ __launch_bounds__(256) void combine_kv(
    const float* __restrict__ P,
    unsigned short* __restrict__ kB,   // pre-offset to row 2048
    unsigned short* __restrict__ vt)   // pre-offset to key 2048
{
  const int j = blockIdx.x * 256 + threadIdx.x;  // 0..524287
  {
    const int row = j >> 9, col = j & 511;
    float v = P[row * 1024 + col] + P[1048576 + row * 1024 + col];
    kB[row * 512 + col] = f2bf(v);
  }
  {
    const int hd = j >> 10, key = j & 1023;
    float v0 = P[key * 1024 + 512 + hd] + P[1048576 + key * 1024 + 512 + hd];
    vt[(size_t)hd * 3072 + key] = f2bf(v0);
  }
}

// ---------------------------------------------------------------------------
// Flash attention, split-KV by 2; Q read directly from fp32 split partials
// (sum*0.125*log2e fused here). Grid (16, 32, 2), 4 waves.
// ---------------------------------------------------------------------------
__global__ __launch_bounds__(256) void attn_k(
    const float* __restrict__ Pq,       // [2][1024][2048] fp32 partials
    const unsigned short* __restrict__ Kb,
    const unsigned short* __restrict__ Vt,
    unsigned short* __restrict__ Op,
    float* __restrict__ Ml)
{
  __shared__ __align__(16) unsigned short sK[2][64 * 64];
  __shared__ __align__(16) unsigned short sV[2][64 * 64];
  __shared__ __align__(16) unsigned short sP[64 * 64];
  const int tid = threadIdx.x;
  const int lane = tid & 63, w = tid >> 6;
  const int ln = lane & 15, qo = lane >> 4;
  const int head = blockIdx.y, kvh = head >> 2;
  const int half = blockIdx.z;
  const int qw = blockIdx.x * 64 + w * 16;
  const int key0 = half * 1536;

  const float QS = 0.18033688011112042f;  // 2^-3 * log2(e)
  const float* qr = Pq + (size_t)(qw + ln) * 2048 + head * 64;
  short8 qf[2];
#pragma unroll
  for (int kc = 0; kc < 2; kc++) {
    const float* q0 = qr + kc * 32 + qo * 8;
    float4 a0 = *(const float4*)(q0);
    float4 a1 = *(const float4*)(q0 + 4);
    float4 b0 = *(const float4*)(q0 + 2097152);
    float4 b1 = *(const float4*)(q0 + 2097152 + 4);
    short8 t;
    t[0] = (short)f2bf((a0.x + b0.x) * QS); t[1] = (short)f2bf((a0.y + b0.y) * QS);
    t[2] = (short)f2bf((a0.z + b0.z) * QS); t[3] = (short)f2bf((a0.w + b0.w) * QS);
    t[4] = (short)f2bf((a1.x + b1.x) * QS); t[5] = (short)f2bf((a1.y + b1.y) * QS);
    t[6] = (short)f2bf((a1.z + b1.z) * QS); t[7] = (short)f2bf((a1.w + b1.w) * QS);
    qf[kc] = t;
  }

  const f32x4 z4 = {0.f, 0.f, 0.f, 0.f};
  f32x4 oacc[4] = {z4, z4, z4, z4};
  float mrun = -1e30f, lrun = 0.f;

  const unsigned short* Kg = Kb + kvh * 64;
  const unsigned short* Vg = Vt + (size_t)(kvh * 64) * 3072;

  stage64<64>(Kg + (size_t)key0 * 512, 512, 0, sK[0], tid);
  stage64<64>(Vg, 3072, key0, sV[0], tid);

  for (int t = 0; t < 24; ++t) {
    const int cur = t & 1;
    VMW0();
    __builtin_amdgcn_s_barrier();
    asm volatile("" ::: "memory");
    if (t + 1 < 24) {
      stage64<64>(Kg + (size_t)(key0 + (t + 1) * 64) * 512, 512, 0, sK[cur ^ 1], tid);
      stage64<64>(Vg, 3072, key0 + (t + 1) * 64, sV[cur ^ 1], tid);
    }

    f32x4 sacc[4] = {z4, z4, z4, z4};
#pragma unroll
    for (int kc = 0; kc < 2; kc++) {
      short8 kf[4];
#pragma unroll
      for (int mi = 0; mi < 4; mi++)
        kf[mi] = lds_frag(sK[cur], mi * 16 + ln, kc * 64 + qo * 16);
      __builtin_amdgcn_s_setprio(1);
#pragma unroll
      for (int mi = 0; mi < 4; mi++)
        sacc[mi] = __builtin_amdgcn_mfma_f32_16x16x32_bf16(kf[mi], qf[kc], sacc[mi], 0, 0, 0);
      __builtin_amdgcn_s_setprio(0);
    }

    float tm = -1e30f;
#pragma unroll
    for (int mi = 0; mi < 4; mi++) {
      float a0 = fmaxf(sacc[mi][0], sacc[mi][1]);
      float a1 = fmaxf(sacc[mi][2], sacc[mi][3]);
      tm = fmaxf(tm, fmaxf(a0, a1));
    }
    tm = fmaxf(tm, __shfl_xor(tm, 16));
    tm = fmaxf(tm, __shfl_xor(tm, 32));

    if (!__all(tm <= mrun + 11.f)) {
      const float mn = fmaxf(mrun, tm);
      const float al = fexp2(mrun - mn);
      lrun *= al;
      mrun = mn;
#pragma unroll
      for (int r = 0; r < 4; r++) {
        float ar = __shfl(al, qo * 4 + r);
#pragma unroll
        for (int ni = 0; ni < 4; ni++) oacc[ni][r] *= ar;
      }
    }

    float ts = 0.f;
#pragma unroll
    for (int mi = 0; mi < 4; mi++) {
      us4 pk;
#pragma unroll
      for (int r = 0; r < 4; r++) {
        float pv = fexp2(sacc[mi][r] - mrun);
        ts += pv;
        pk[r] = f2bf(pv);
      }
      const int row = w * 16 + ln;
      const int g16 = (2 * mi + (qo >> 1)) ^ (ln & 7);
      *(us4*)((char*)sP + row * 128 + (g16 << 4) + ((qo & 1) << 3)) = pk;
    }
    ts += __shfl_xor(ts, 16);
    ts += __shfl_xor(ts, 32);
    lrun += ts;

#pragma unroll
    for (int ks = 0; ks < 2; ks++) {
      short8 pf = lds_frag(sP, w * 16 + ln, ks * 64 + qo * 16);
      short8 vf[4];
#pragma unroll
      for (int ni = 0; ni < 4; ni++)
        vf[ni] = lds_frag(sV[cur], ni * 16 + ln, ks * 64 + qo * 16);
      __builtin_amdgcn_s_setprio(1);
#pragma unroll
      for (int ni = 0; ni < 4; ni++)
        oacc[ni] = __builtin_amdgcn_mfma_f32_16x16x32_bf16(pf, vf[ni], oacc[ni], 0, 0, 0);
      __builtin_amdgcn_s_setprio(0);
    }
    LGKM0();
  }

  if (qo == 0)
    *(float2*)&Ml[((size_t)(half * 32 + head) * 1024 + qw + ln) * 2] =
        make_float2(mrun, lrun);
#pragma unroll
  for (int r = 0; r < 4; r++)
#pragma unroll
    for (int ni = 0; ni < 4; ni++)
      Op[(size_t)half * 2097152 + (size_t)(qw + qo * 4 + r) * 2048 + head * 64 + ni * 16 + ln] =
          f2bf(oacc[ni][r]);
}

__global__ __launch_bounds__(256) void attn_combine(
    const unsigned short* __restrict__ Op,
    const float* __restrict__ Ml,
    unsigned short* __restrict__ O)
{
  const int f = blockIdx.x * 256 + threadIdx.x;
  const int q = f >> 9;
  const int c = (f & 511) * 4;
  const int head = c >> 6;
  const float2 ml0 = *(const float2*)&Ml[((size_t)head * 1024 + q) * 2];
  const float2 ml1 = *(const float2*)&Ml[((size_t)(32 + head) * 1024 + q) * 2];
  const float m = fmaxf(ml0.x, ml1.x);
  const float w0 = fexp2(ml0.x - m), w1 = fexp2(ml1.x - m);
  const float inv = 1.f / (w0 * ml0.y + w1 * ml1.y);
  const us4 o0 = *(const us4*)&Op[(size_t)q * 2048 + c];
  const us4 o1 = *(const us4*)&Op[2097152 + (size_t)q * 2048 + c];
  us4 o;
#pragma unroll
  for (int j = 0; j < 4; j++)
    o[j] = f2bf((w0 * bf2f(o0[j]) + w1 * bf2f(o1[j])) * inv);
  *(us4*)&O[(size_t)q * 2048 + c] = o;
}

// ---------------------------------------------------------------------------
// RMSNorm variants. Each block = one row of 2048.
// ---------------------------------------------------------------------------
__global__ __launch_bounds__(256) void rmsnorm_k(const float* __restrict__ in,
                                                 const float* __restrict__ w,
                                                 unsigned short* __restrict__ out) {
  const int row = blockIdx.x;
  const int tid = threadIdx.x;
  const float* x = in + (size_t)row * 2048;
  float4 a = ((const float4*)x)[tid * 2];
  float4 b = ((const float4*)x)[tid * 2 + 1];
  float ss = a.x * a.x + a.y * a.y + a.z * a.z + a.w * a.w +
             b.x * b.x + b.y * b.y + b.z * b.z + b.w * b.w;
#pragma unroll
  for (int d = 1; d < 64; d <<= 1) ss += __shfl_xor(ss, d);
  __shared__ float red[4];
  if ((tid & 63) == 0) red[tid >> 6] = ss;
  __syncthreads();
  float sc = rsqrtf((red[0] + red[1] + red[2] + red[3]) * (1.f / 2048.f) + 1e-6f);
  float4 wa = ((const float4*)w)[tid * 2];
  float4 wb = ((const float4*)w)[tid * 2 + 1];
  us4 o1, o2;
  o1[0] = f2bf(a.x * sc * wa.x); o1[1] = f2bf(a.y * sc * wa.y);
  o1[2] = f2bf(a.z * sc * wa.z); o1[3] = f2bf(a.w * sc * wa.w);
  o2[0] = f2bf(b.x * sc * wb.x); o2[1] = f2bf(b.y * sc * wb.y);
  o2[2] = f2bf(b.z * sc * wb.z); o2[3] = f2bf(b.w * sc * wb.w);
  us4* op = (us4*)&out[(size_t)row * 2048 + tid * 8];
  op[0] = o1; op[1] = o2;
}

// ctf += P0+P1 (O-proj residual), then norm -> out (bf16).
__global__ __launch_bounds__(256) void rmsnorm_add_k(
    float* __restrict__ ctf, const float* __restrict__ P,
    const float* __restrict__ w, unsigned short* __restrict__ out) {
  const int row = blockIdx.x;
  const int tid = threadIdx.x;
  const size_t base = (size_t)row * 2048 + tid * 8;
  float t[8];
  float4 c0 = *(const float4*)&ctf[base], c1 = *(const float4*)&ctf[base + 4];
  float4 p0 = *(const float4*)&P[base], p1 = *(const float4*)&P[base + 4];
  float4 q0 = *(const float4*)&P[base + 2097152], q1 = *(const float4*)&P[base + 2097152 + 4];
  t[0] = c0.x + p0.x + q0.x; t[1] = c0.y + p0.y + q0.y;
  t[2] = c0.z + p0.z + q0.z; t[3] = c0.w + p0.w + q0.w;
  t[4] = c1.x + p1.x + q1.x; t[5] = c1.y + p1.y + q1.y;
  t[6] = c1.z + p1.z + q1.z; t[7] = c1.w + p1.w + q1.w;
  *(float4*)&ctf[base] = make_float4(t[0], t[1], t[2], t[3]);
  *(float4*)&ctf[base + 4] = make_float4(t[4], t[5], t[6], t[7]);
  float ss = 0.f;
#pragma unroll
  for (int i = 0; i < 8; i++) ss += t[i] * t[i];
#pragma unroll
  for (int d = 1; d < 64; d <<= 1) ss += __shfl_xor(ss, d);
  __shared__ float red[4];
  if ((tid & 63) == 0) red[tid >> 6] = ss;
  __syncthreads();
  float sc = rsqrtf((red[0] + red[1] + red[2] + red[3]) * (1.f / 2048.f) + 1e-6f);
  us4 o1, o2;
#pragma unroll
  for (int i = 0; i < 4; i++) o1[i] = f2bf(t[i] * sc * w[tid * 8 + i]);
#pragma unroll
  for (int i = 0; i < 4; i++) o2[i] = f2bf(t[4 + i] * sc * w[tid * 8 + 4 + i]);
  us4* op = (us4*)&out[base];
  op[0] = o1; op[1] = o2;
}

// t = P0+P1+y (down-proj + mlp residual); ctf = t; ctb = bf16(t); y <- norm(t)*w.
__global__ __launch_bounds__(256) void rmsnorm_add2_k(
    const float* __restrict__ P, unsigned short* __restrict__ yb,
    float* __restrict__ ctf, unsigned short* __restrict__ ctb,
    const float* __restrict__ w) {
  const int row = blockIdx.x;
  const int tid = threadIdx.x;
  const size_t base = (size_t)row * 2048 + tid * 8;
  float t[8];
  float4 p0 = *(const float4*)&P[base], p1 = *(const float4*)&P[base + 4];
  float4 q0 = *(const float4*)&P[base + 2097152], q1 = *(const float4*)&P[base + 2097152 + 4];
  us4 y0 = *(const us4*)&yb[base], y1 = *(const us4*)&yb[base + 4];
  t[0] = p0.x + q0.x + bf2f(y0[0]); t[1] = p0.y + q0.y + bf2f(y0[1]);
  t[2] = p0.z + q0.z + bf2f(y0[2]); t[3] = p0.w + q0.w + bf2f(y0[3]);
  t[4] = p1.x + q1.x + bf2f(y1[0]); t[5] = p1.y + q1.y + bf2f(y1[1]);
  t[6] = p1.z + q1.z + bf2f(y1[2]); t[7] = p1.w + q1.w + bf2f(y1[3]);
  *(float4*)&ctf[base] = make_float4(t[0], t[1], t[2], t[3]);
  *(float4*)&ctf[base + 4] = make_float4(t[4], t[5], t[6], t[7]);
  us4 cb0, cb1;
#pragma unroll
  for (int i = 0; i < 4; i++) { cb0[i] = f2bf(t[i]); cb1[i] = f2bf(t[4 + i]); }
  *(us4*)&ctb[base] = cb0; *(us4*)&ctb[base + 4] = cb1;
  float ss = 0.f;
#pragma unroll
  for (int i = 0; i < 8; i++) ss += t[i] * t[i];
#pragma unroll
  for (int d = 1; d < 64; d <<= 1) ss += __shfl_xor(ss, d);
  __shared__ float red[4];
  if ((tid & 63) == 0) red[tid >> 6] = ss;
  __syncthreads();
  float sc = rsqrtf((red[0] + red[1] + red[2] + red[3]) * (1.f / 2048.f) + 1e-6f);
  us4 o1, o2;
#pragma unroll
  for (int i = 0; i < 4; i++) o1[i] = f2bf(t[i] * sc * w[tid * 8 + i]);
#pragma unroll
  for (int i = 0; i < 4; i++) o2[i] = f2bf(t[4 + i] * sc * w[tid * 8 + 4 + i]);
  us4* op = (us4*)&yb[base];
  op[0] = o1; op[1] = o2;
}

// Final: out = P0+P1+y (fp32).
__global__ __launch_bounds__(256) void combine2_k(
    const float* __restrict__ P, const unsigned short* __restrict__ yb,
    float* __restrict__ out) {
  const int j = blockIdx.x * 256 + threadIdx.x;  // float4 idx, 524288
  float4 p0 = ((const float4*)P)[j];
  float4 p1 = ((const float4*)P)[j + 524288];
  us4 y = ((const us4*)yb)[j];
  float4 o;
  o.x = p0.x + p1.x + bf2f(y[0]); o.y = p0.y + p1.y + bf2f(y[1]);
  o.z = p0.z + p1.z + bf2f(y[2]); o.w = p0.w + p1.w + bf2f(y[3]);
  ((float4*)out)[j] = o;
}

// ---------------------------------------------------------------------------
// Segment-major conversion of all fp32 inputs to bf16 (+ ct init fused).
// gate/up written 16-row interleaved into guB.
// ---------------------------------------------------------------------------
__global__ __launch_bounds__(256) void cvt_all(
    const float* __restrict__ hid, const float* __restrict__ qw,
    const float* __restrict__ kw, const float* __restrict__ vw,
    const float* __restrict__ ow, const float* __restrict__ gw,
    const float* __restrict__ uw, const float* __restrict__ dw,
    unsigned short* __restrict__ hb, unsigned short* __restrict__ qwB,
    unsigned short* __restrict__ kwB, unsigned short* __restrict__ vwB,
    unsigned short* __restrict__ owB, unsigned short* __restrict__ guB,
    unsigned short* __restrict__ dwB,
    float* __restrict__ ctf, unsigned short* __restrict__ ctb)
{
  const int gid = blockIdx.x * 256 + threadIdx.x;
  const int gs = gridDim.x * 256;
  for (int i = gid; i < 1048576; i += gs) {
    float4 v = ((const float4*)hid)[i];
    us4 o; o[0] = f2bf(v.x); o[1] = f2bf(v.y); o[2] = f2bf(v.z); o[3] = f2bf(v.w);
    ((us4*)hb)[i] = o;
    if (i >= 524288) { ((float4*)ctf)[i - 524288] = v; ((us4*)ctb)[i - 524288] = o; }
  }
  for (int i = gid; i < 1048576; i += gs) {
    float4 v = ((const float4*)qw)[i];
    us4 o; o[0] = f2bf(v.x); o[1] = f2bf(v.y); o[2] = f2bf(v.z); o[3] = f2bf(v.w);
    ((us4*)qwB)[i] = o;
  }
  for (int i = gid; i < 262144; i += gs) {
    float4 v = ((const float4*)kw)[i];
    us4 o; o[0] = f2bf(v.x); o[1] = f2bf(v.y); o[2] = f2bf(v.z); o[3] = f2bf(v.w);
    ((us4*)kwB)[i] = o;
  }
  for (int i = gid; i < 262144; i += gs) {
    float4 v = ((const float4*)vw)[i];
    us4 o; o[0] = f2bf(v.x); o[1] = f2bf(v.y); o[2] = f2bf(v.z); o[3] = f2bf(v.w);
    ((us4*)vwB)[i] = o;
  }
  for (int i = gid; i < 1048576; i += gs) {
    float4 v = ((const float4*)ow)[i];
    us4 o; o[0] = f2bf(v.x); o[1] = f2bf(v.y); o[2] = f2bf(v.z); o[3] = f2bf(v.w);
    ((us4*)owB)[i] = o;
  }
  for (int i = gid; i < 2883584; i += gs) {
    float4 v = ((const float4*)gw)[i];
    us4 o; o[0] = f2bf(v.x); o[1] = f2bf(v.y); o[2] = f2bf(v.z); o[3] = f2bf(v.w);
    const int row = i >> 9, c4 = i & 511;
    ((us4*)guB)[((((row >> 4) << 5) + (row & 15)) << 9) + c4] = o;
  }
  for (int i = gid; i < 2883584; i += gs) {
    float4 v = ((const float4*)uw)[i];
    us4 o; o[0] = f2bf(v.x); o[1] = f2bf(v.y); o[2] = f2bf(v.z); o[3] = f2bf(v.w);
    const int row = i >> 9, c4 = i & 511;
    ((us4*)guB)[((((row >> 4) << 5) + (row & 15) + 16) << 9) + c4] = o;
  }
  for (int i = gid; i < 2883584; i += gs) {
    float4 v = ((const float4*)dw)[i];
    us4 o; o[0] = f2bf(v.x); o[1] = f2bf(v.y); o[2] = f2bf(v.z); o[3] = f2bf(v.w);
    ((us4*)dwB)[i] = o;
  }
}

// ---------------------------------------------------------------------------
extern "C" void kernel_launch(void* const* d_in, const int* in_sizes, int n_in,
                              void* d_out, int out_size, void* d_ws, size_t ws_size,
                              hipStream_t stream) {
  (void)in_sizes; (void)n_in; (void)out_size; (void)ws_size;
  const float* hidden = (const float*)d_in[0];
  const float* q_w  = (const float*)d_in[1];
  const float* k_w  = (const float*)d_in[2];
  const float* v_w  = (const float*)d_in[3];
  const float* o_w  = (const float*)d_in[4];
  const float* a_nw = (const float*)d_in[5];
  const float* m_nw = (const float*)d_in[6];
  const float* g_w  = (const float*)d_in[7];
  const float* u_w  = (const float*)d_in[8];
  const float* dn_w = (const float*)d_in[9];
  float* out = (float*)d_out;

  char* p = (char*)d_ws;
  size_t off = 0;
  auto take = [&](size_t bytes) -> char* {
    char* r = p + off;
    off += (bytes + 255) & ~(size_t)255;
    return r;
  };
  float* ctf          = (float*)take((size_t)1024 * 2048 * 4);
  unsigned short* ctb = (unsigned short*)take((size_t)1024 * 2048 * 2);
  unsigned short* xb  = (unsigned short*)take((size_t)1024 * 2048 * 2);
  unsigned short* hb  = (unsigned short*)take((size_t)2048 * 2048 * 2);
  unsigned short* qwB = (unsigned short*)take((size_t)2048 * 2048 * 2);
  unsigned short* kwB = (unsigned short*)take((size_t)512 * 2048 * 2);
  unsigned short* vwB = (unsigned short*)take((size_t)512 * 2048 * 2);
  unsigned short* owB = (unsigned short*)take((size_t)2048 * 2048 * 2);
  unsigned short* guB = (unsigned short*)take((size_t)11264 * 2048 * 2);
  unsigned short* dwB = (unsigned short*)take((size_t)2048 * 5632 * 2);
  unsigned short* kB  = (unsigned short*)take((size_t)3072 * 512 * 2);
  unsigned short* vtB = (unsigned short*)take((size_t)512 * 3072 * 2);
  unsigned short* oB  = (unsigned short*)take((size_t)1024 * 2048 * 2);
  unsigned short* gtB = (unsigned short*)take((size_t)1024 * 5632 * 2);
  float* Pd           = (float*)take((size_t)2 * 1024 * 2048 * 4);  // split-K partials

  unsigned short* Op = xb;            // attn partials alias xb+hb (dead there)
  float* Ml = (float*)((char*)xb + (size_t)2 * 1024 * 2048 * 2);
  float* PKV = (float*)hb;            // KV split partials alias hb (dead in-loop)

  dim3 blk(256);
  cvt_all<<<dim3(2048), blk, 0, stream>>>(hidden, q_w, k_w, v_w, o_w, g_w, u_w, dn_w,
                                          hb, qwB, kwB, vwB, owB, guB, dwB, ctf, ctb);

  gemm_dual<0><<<dim3(8, 32), blk, 0, stream>>>(hb, kwB, vwB, 2048, kB, vtB, nullptr, 512, 3072);

  for (int it = 0; it < 2; it++) {
    if (it == 0)
      rmsnorm_k<<<dim3(1024), blk, 0, stream>>>(ctf, a_nw, xb);
    else
      rmsnorm_add2_k<<<dim3(1024), blk, 0, stream>>>(Pd, xb, ctf, ctb, a_nw);
    gemm_split<<<dim3(16, 16, 2), blk, 0, stream>>>(xb, qwB, 2048, Pd, 2048);
    gemm_dual<1><<<dim3(8, 16, 2), blk, 0, stream>>>(ctb, kwB, vwB, 2048,
                                                     nullptr, nullptr, PKV, 0, 0);
    combine_kv<<<dim3(2048), blk, 0, stream>>>(PKV, kB + (size_t)2048 * 512, vtB + 2048);
    attn_k<<<dim3(16, 32, 2), blk, 0, stream>>>(Pd, kB, vtB, Op, Ml);
    attn_combine<<<dim3(2048), blk, 0, stream>>>(Op, Ml, oB);
    gemm_split<<<dim3(16, 16, 2), blk, 0, stream>>>(oB, owB, 2048, Pd, 2048);
    rmsnorm_add_k<<<dim3(1024), blk, 0, stream>>>(ctf, Pd, m_nw, xb);
    gemm_gu<<<dim3(88, 8), blk, 0, stream>>>(xb, guB, gtB);
    gemm_split<<<dim3(16, 16, 2), blk, 0, stream>>>(gtB, dwB, 5632, Pd, 2048);
  }
  combine2_k<<<dim3(2048), blk, 0, stream>>>(Pd, xb, out);
}